// Round 8
// baseline (4878.130 us; speedup 1.0000x reference)
//
#include <hip/hip_runtime.h>
#include <math.h>

typedef __attribute__((ext_vector_type(8))) short v8s;
typedef __attribute__((ext_vector_type(4))) short v4s;
typedef __attribute__((ext_vector_type(4))) float v4f;

#define AP 136              // padded LDS row stride (shorts); 272 B rows keep 16B align
#define OFF_W3 0
#define OFF_WI 524288
#define OFF_W1 528384
#define OFF_W2 544768
#define OFF_WR 561152
#define LO     565248       // lo-residual region offset (shorts)
#define WF_TOTAL2 1130496   // hi+lo regions (shorts, 2.26 MB)
#define KBUF_BYTE 2260992   // float kbuf[32 bg][2 par][1024]  (256 KB)
#define FLG_BYTE  2523136   // uint flags[32 bg][16 tr] @ 64 B spacing (32 KB)
#define FLG_SIZE  32768     // total ws footprint = 2555904 B (= r6 proven)

static __device__ __forceinline__ float bf2f(unsigned short s){
    union { unsigned u; float f; } v; v.u = ((unsigned)s) << 16; return v.f;
}
static __device__ __forceinline__ unsigned short f2bf(float f){
    union { float ff; unsigned u; } v; v.ff = f;
    return (unsigned short)((v.u + 0x7FFFu + ((v.u >> 16) & 1u)) >> 16);
}
// triple split: v = h + m + l + eps, |eps| <= 2^-27 |v|
static __device__ __forceinline__ void split3(float v, unsigned short& h,
                                              unsigned short& m, unsigned short& l){
    h = f2bf(v);  float r1 = v - bf2f(h);
    m = f2bf(r1); float r2 = r1 - bf2f(m);
    l = f2bf(r2);
}
static __device__ __forceinline__ float softplus_f(float x){
    float t = __builtin_amdgcn_exp2f(x * 1.44269504088896341f);
    float r = 0.69314718055994531f * __builtin_amdgcn_logf(1.0f + t);
    return (x > 20.0f) ? x : r;
}
static __device__ __forceinline__ float tanh_f(float x){
    float xc = fminf(fmaxf(x, -9.0f), 9.0f);
    float t = __builtin_amdgcn_exp2f(xc * 2.8853900817779268f); // e^{2x}
    float d = t + 1.0f;
    float r = __builtin_amdgcn_rcpf(d);
    r = r * (2.0f - d * r);                                     // NR refine
    return (t - 1.0f) * r;
}

#define MFMA(acc, a, b) acc = __builtin_amdgcn_mfma_f32_16x16x32_bf16(a, b, acc, 0, 0, 0)

// ---------------------------------------------------------------------------
// fp32 weight -> bf16 hi + bf16 lo-residual MFMA B-fragment layout:
// frag elem = W[kt*32 + (lane>>4)*8 + j][nt*16 + (lane&15)]
// ---------------------------------------------------------------------------
__global__ void prep_kernel(const float* __restrict__ W,
                            unsigned short* __restrict__ dst,
                            int KT, int N, int total, int base, int wlimit){
    int tid = blockIdx.x * 256 + threadIdx.x;
    if (tid >= total) return;
    int j  = tid & 7;
    int l  = (tid >> 3) & 63;
    int t2 = tid >> 9;
    int kt = t2 % KT;
    int nt = t2 / KT;
    int row = kt * 32 + (l >> 4) * 8 + j;
    int col = nt * 16 + (l & 15);
    float w = W[(size_t)row * N + col];
    unsigned short h = f2bf(w);
    if (base + tid < wlimit)      dst[base + tid]      = h;
    if (base + LO + tid < wlimit) dst[base + LO + tid] = f2bf(w - bf2f(h));
}

// all-wave flag poll: wave proceeds when all 16 producer flags >= tgt
static __device__ __forceinline__ void poll_flags(const unsigned int* __restrict__ teamflg,
                                                  unsigned tgt, int lane){
    unsigned it = 0;
    for (;;){
        unsigned fv = tgt;
        if (lane < 16)
            fv = __hip_atomic_load(&teamflg[lane * 16], __ATOMIC_RELAXED,
                                   __HIP_MEMORY_SCOPE_AGENT);
        if (__all((int)(fv >= tgt))) break;
        if (++it >= (1u << 22)) break;   // terminate-don't-hang safety
        __builtin_amdgcn_s_sleep(1);
    }
}

// ---------------------------------------------------------------------------
// 5-MFMA fragment GEMM (A-triple from LDS x B-double from global), M=8 rows.
// 4 waves; wave w handles pair-columns p = w, w+4, ...
// MODE 0: +bias -> zx (fp32 LDS, rows<8)   MODE 1: +bias, softplus -> triple A-out
// MODE 4: +bias +x_last -> out fp32 global (rows<8)
// ---------------------------------------------------------------------------
template<int KT, int MODE>
static __device__ __forceinline__ void gemm5(
    const unsigned short* __restrict__ wf, int wbase, int npairs,
    const unsigned short* Ah, const unsigned short* Am, const unsigned short* Al,
    unsigned short* Aoh, unsigned short* Aom, unsigned short* Aol,
    float* zx,
    const float* __restrict__ bias_g,
    const float* __restrict__ xlast, float* __restrict__ outg, int bg)
{
    const int tid  = threadIdx.x;
    const int lane = tid & 63;
    const int wid  = tid >> 6;
    const int l15  = lane & 15;
    const int q    = lane >> 4;

    v8s ah[KT], am[KT], al[KT];
#pragma unroll
    for (int kt = 0; kt < KT; ++kt){
        ah[kt] = *(const v8s*)&Ah[l15 * AP + kt * 32 + q * 8];
        am[kt] = *(const v8s*)&Am[l15 * AP + kt * 32 + q * 8];
        al[kt] = *(const v8s*)&Al[l15 * AP + kt * 32 + q * 8];
    }

    for (int p = wid; p < npairs; p += 4){
        const int nt0 = 2 * p, nt1 = 2 * p + 1;
        v4f acc0 = {0.f, 0.f, 0.f, 0.f};
        v4f acc1 = {0.f, 0.f, 0.f, 0.f};
#pragma unroll
        for (int kt = 0; kt < KT; ++kt){
            int o0 = wbase + ((nt0 * KT + kt) * 64 + lane) * 8;
            int o1 = wbase + ((nt1 * KT + kt) * 64 + lane) * 8;
            v8s bh0 = *(const v8s*)&wf[o0];
            v8s bl0 = *(const v8s*)&wf[o0 + LO];
            v8s bh1 = *(const v8s*)&wf[o1];
            v8s bl1 = *(const v8s*)&wf[o1 + LO];
            MFMA(acc0, ah[kt], bh0); MFMA(acc0, am[kt], bh0); MFMA(acc0, al[kt], bh0);
            MFMA(acc0, ah[kt], bl0); MFMA(acc0, am[kt], bl0);
            MFMA(acc1, ah[kt], bh1); MFMA(acc1, am[kt], bh1); MFMA(acc1, al[kt], bh1);
            MFMA(acc1, ah[kt], bl1); MFMA(acc1, am[kt], bl1);
        }
        const int c0 = nt0 * 16 + l15, c1 = nt1 * 16 + l15;

        if (MODE == 0){
#pragma unroll
            for (int r = 0; r < 4; ++r){
                int b = q * 4 + r;
                if (b < 8){
                    zx[b * 128 + c0] = acc0[r] + bias_g[c0];
                    zx[b * 128 + c1] = acc1[r] + bias_g[c1];
                }
            }
        } else if (MODE == 1){
            // rows 8-15 produce benign finite garbage that only propagates to
            // rows 8-15 downstream (GEMM rows independent) -- no guard needed
#pragma unroll
            for (int r = 0; r < 4; ++r){
                int b = q * 4 + r;
                float v0 = softplus_f(acc0[r] + bias_g[c0]);
                float v1 = softplus_f(acc1[r] + bias_g[c1]);
                unsigned short h, m, l;
                split3(v0, h, m, l); Aoh[b*AP+c0]=h; Aom[b*AP+c0]=m; Aol[b*AP+c0]=l;
                split3(v1, h, m, l); Aoh[b*AP+c1]=h; Aom[b*AP+c1]=m; Aol[b*AP+c1]=l;
            }
        } else { // MODE 4
#pragma unroll
            for (int r = 0; r < 4; ++r){
                int b = q * 4 + r;
                if (b < 8){
                    int gb = bg * 8 + b;
                    outg[gb * 32 + c0] = acc0[r] + bias_g[c0] + xlast[gb * 32 + c0];
                    outg[gb * 32 + c1] = acc1[r] + bias_g[c1] + xlast[gb * 32 + c1];
                }
            }
        }
    }
}

// ---------------------------------------------------------------------------
// Persistent team kernel: 512 blocks = 32 batch-groups (M=8 rows) x 16-block
// teams; 2 co-resident blocks/CU provide HW-scheduled latency overlap.
// Block (bg, tr) owns W3 columns [tr*256, tr*256+256), register-cached.
// ---------------------------------------------------------------------------
__global__ __launch_bounds__(256) void cde_kernel(
    const float* __restrict__ coeffs,
    const float* __restrict__ x_last,
    const float* __restrict__ bi,
    const float* __restrict__ b1,
    const float* __restrict__ b2,
    const float* __restrict__ b3,
    const float* __restrict__ br,
    const unsigned short* __restrict__ wf,
    float* __restrict__ kbuf,
    unsigned int* __restrict__ flgs,
    float* __restrict__ outg)
{
    __shared__ unsigned short A0h[16*AP] __attribute__((aligned(16)));
    __shared__ unsigned short A0m[16*AP] __attribute__((aligned(16)));
    __shared__ unsigned short A0l[16*AP] __attribute__((aligned(16)));
    __shared__ unsigned short A1h[16*AP] __attribute__((aligned(16)));
    __shared__ unsigned short A1m[16*AP] __attribute__((aligned(16)));
    __shared__ unsigned short A1l[16*AP] __attribute__((aligned(16)));
    __shared__ unsigned short A2h[16*AP] __attribute__((aligned(16)));
    __shared__ unsigned short A2m[16*AP] __attribute__((aligned(16)));
    __shared__ unsigned short A2l[16*AP] __attribute__((aligned(16)));
    __shared__ float dval[512];
    __shared__ float zx[1024];

    const int tid  = threadIdx.x;
    const int lane = tid & 63;
    const int wid  = tid >> 6;
    const int l15  = lane & 15;
    const int q    = lane >> 4;
    const int bx   = blockIdx.x;
    // team members share bx&7 (XCD-local); bits: team = {b8b7, b2b1b0}, tr = b6..b3
    const int team = (bx & 7) * 4 + (bx >> 7);   // 0..31
    const int tr   = (bx >> 3) & 15;
    const int bg   = team;

    float*        kb0     = kbuf + bg * 2048;    // [par][1024]
    unsigned int* teamflg = flgs + bg * 256;     // 16 flags @ 64 B (16 uints)
    unsigned int* myflag  = teamflg + tr * 16;

    for (int e = tid; e < 16*AP; e += 256){
        A0h[e]=0; A0m[e]=0; A0l[e]=0; A1h[e]=0; A1m[e]=0; A1l[e]=0;
        A2h[e]=0; A2m[e]=0; A2l[e]=0;
    }
    for (int e = tid; e < 512; e += 256) dval[e] = 0.f;

    // preload this block's W3 slice fragments (hi+lo) into registers
    v8s w3h[2][2][4], w3l[2][2][4];   // [pi][tile][kt]
#pragma unroll
    for (int pi = 0; pi < 2; ++pi){
        int p = wid + 4 * pi;
#pragma unroll
        for (int i = 0; i < 2; ++i){
            int ntg = tr * 16 + 2 * p + i;
#pragma unroll
            for (int kt = 0; kt < 4; ++kt){
                int o = ((ntg * 4 + kt) * 64 + lane) * 8;   // OFF_W3 = 0
                w3h[pi][i][kt] = *(const v8s*)&wf[o];
                w3l[pi][i][kt] = *(const v8s*)&wf[o + LO];
            }
        }
    }

    // initial A0 = a0 = coeffs[:, 0, 0:32] rows 0-7, triple-split
    for (int e = tid; e < 256; e += 256){
        int r = e >> 5, c = e & 31;
        float v = coeffs[((size_t)(bg * 8 + r) * 64) * 128 + c];
        unsigned short h, m, l; split3(v, h, m, l);
        A0h[r*AP+c] = h; A0m[r*AP+c] = m; A0l[r*AP+c] = l;
    }
    __syncthreads();
    gemm5<1, 0>(wf, OFF_WI, 4, A0h, A0m, A0l, nullptr, nullptr, nullptr,
                zx, bi, nullptr, nullptr, bg);
    __syncthreads();

    // thread-private RK4 state: thread owns elems e = tid*4 .. +3 (8x128 total)
    float zp[4], kap[4], k1p[4], k2p[4];
#pragma unroll
    for (int i = 0; i < 4; ++i){ zp[i] = zx[tid*4 + i]; kap[i]=0.f; k1p[i]=0.f; k2p[i]=0.f; }

    const int arow  = tid >> 5;          // (tid*4)>>7, rows 0-7
    const int acolS = (tid & 31) * 4;    // (tid*4)&127

    for (int st = 0; st < 256; ++st){
        const int stp = st >> 2, sub = st & 3;
        int idx; float frac;
        if      (sub == 0){ idx = stp; frac = 0.f; }
        else if (sub == 1){ idx = stp; frac = 1.f / 3.f; }
        else if (sub == 2){ idx = stp; frac = 2.f / 3.f; }
        else { idx = (stp < 63) ? stp + 1 : 63; frac = (stp < 63) ? 0.f : 1.f; }

        // spline derivative rows 0-7 (exact fp32)
        for (int e = tid; e < 256; e += 256){
            int r = e >> 5, c = e & 31;
            size_t base = ((size_t)(bg * 8 + r) * 64 + idx) * 128;
            dval[e] = coeffs[base + 32 + c]
                    + (coeffs[base + 64 + c] + coeffs[base + 96 + c] * frac) * frac;
        }
        // stage A0 from private state (8 B LDS stores)
        {
            v4s vh, vm, vl;
#pragma unroll
            for (int i = 0; i < 4; ++i){
                float v = (sub == 0) ? zp[i] : kap[i];
                unsigned short h, m, l; split3(v, h, m, l);
                vh[i] = (short)h; vm[i] = (short)m; vl[i] = (short)l;
            }
            *(v4s*)&A0h[arow*AP + acolS] = vh;
            *(v4s*)&A0m[arow*AP + acolS] = vm;
            *(v4s*)&A0l[arow*AP + acolS] = vl;
        }
        __syncthreads();
        gemm5<4, 1>(wf, OFF_W1, 4, A0h, A0m, A0l, A1h, A1m, A1l,
                    nullptr, b1, nullptr, nullptr, bg);
        __syncthreads();
        gemm5<4, 1>(wf, OFF_W2, 4, A1h, A1m, A1l, A2h, A2m, A2l,
                    nullptr, b2, nullptr, nullptr, bg);
        __syncthreads();

        // W3 slice with register B-fragments -> k slice (rows 0-7)
        const int par = st & 1;
        float* kbw = kb0 + par * 1024;
        {
            v8s ah[4], am[4], al[4];
#pragma unroll
            for (int kt = 0; kt < 4; ++kt){
                ah[kt] = *(const v8s*)&A2h[l15*AP + kt*32 + q*8];
                am[kt] = *(const v8s*)&A2m[l15*AP + kt*32 + q*8];
                al[kt] = *(const v8s*)&A2l[l15*AP + kt*32 + q*8];
            }
            float dv0[4], dv1[4];
#pragma unroll
            for (int r = 0; r < 4; ++r){
                dv0[r] = dval[(q*4 + r) * 32 + l15];
                dv1[r] = dval[(q*4 + r) * 32 + 16 + l15];
            }
#pragma unroll
            for (int pi = 0; pi < 2; ++pi){
                int p = wid + 4 * pi;
                v4f acc0 = {0.f,0.f,0.f,0.f}, acc1 = {0.f,0.f,0.f,0.f};
#pragma unroll
                for (int kt = 0; kt < 4; ++kt){
                    MFMA(acc0, ah[kt], w3h[pi][0][kt]); MFMA(acc0, am[kt], w3h[pi][0][kt]);
                    MFMA(acc0, al[kt], w3h[pi][0][kt]);
                    MFMA(acc0, ah[kt], w3l[pi][0][kt]); MFMA(acc0, am[kt], w3l[pi][0][kt]);
                    MFMA(acc1, ah[kt], w3h[pi][1][kt]); MFMA(acc1, am[kt], w3h[pi][1][kt]);
                    MFMA(acc1, al[kt], w3h[pi][1][kt]);
                    MFMA(acc1, ah[kt], w3l[pi][1][kt]); MFMA(acc1, am[kt], w3l[pi][1][kt]);
                }
                const int cg0 = tr * 256 + p * 32 + l15;   // global W3 col
                float s4[4];
#pragma unroll
                for (int r = 0; r < 4; ++r){
                    float u0 = acc0[r] + b3[cg0];
                    float u1 = acc1[r] + b3[cg0 + 16];
                    s4[r] = tanh_f(u0) * dv0[r] + tanh_f(u1) * dv1[r];
                }
#pragma unroll
                for (int sm = 1; sm <= 8; sm <<= 1){
#pragma unroll
                    for (int r = 0; r < 4; ++r) s4[r] += __shfl_xor(s4[r], sm);
                }
                if (l15 == 0 && q < 2){
#pragma unroll
                    for (int r = 0; r < 4; ++r)
                        __hip_atomic_store(&kbw[(q*4 + r) * 128 + tr * 8 + p], s4[r],
                                           __ATOMIC_RELAXED, __HIP_MEMORY_SCOPE_AGENT);
                }
            }
        }
        __syncthreads();   // drains kbuf stores (vmcnt) for all waves
        if (tid == 0)
            __hip_atomic_store(myflag, (unsigned)(st + 1),
                               __ATOMIC_RELEASE, __HIP_MEMORY_SCOPE_AGENT);
        // every wave polls independently (no extra barrier needed)
        poll_flags(teamflg, (unsigned)(st + 1), lane);

        float kv[4];
#pragma unroll
        for (int i = 0; i < 4; ++i)
            kv[i] = __hip_atomic_load(&kbw[tid*4 + i], __ATOMIC_RELAXED,
                                      __HIP_MEMORY_SCOPE_AGENT);
#pragma unroll
        for (int i = 0; i < 4; ++i){
            float k = kv[i];
            if      (sub == 0){ k1p[i] = k; kap[i] = zp[i] + k * (1.f/3.f); }
            else if (sub == 1){ k2p[i] = k; kap[i] = zp[i] + (k - k1p[i] * (1.f/3.f)); }
            else if (sub == 2){ kap[i] = zp[i] + (k1p[i] - k2p[i] + k); }
            else { zp[i] = zp[i] + (6.f*k2p[i] - 2.f*k1p[i]
                                    + 3.f*(kap[i] - zp[i]) + k) * 0.125f; }
        }
    }

    // out = x_last + z @ Wr + br  (team blocks write identical values)
    {
        v4s vh, vm, vl;
#pragma unroll
        for (int i = 0; i < 4; ++i){
            unsigned short h, m, l; split3(zp[i], h, m, l);
            vh[i] = (short)h; vm[i] = (short)m; vl[i] = (short)l;
        }
        *(v4s*)&A0h[arow*AP + acolS] = vh;
        *(v4s*)&A0m[arow*AP + acolS] = vm;
        *(v4s*)&A0l[arow*AP + acolS] = vl;
    }
    __syncthreads();
    gemm5<4, 4>(wf, OFF_WR, 1, A0h, A0m, A0l, nullptr, nullptr, nullptr,
                nullptr, br, x_last, outg, bg);
}

extern "C" void kernel_launch(void* const* d_in, const int* in_sizes, int n_in,
                              void* d_out, int out_size, void* d_ws, size_t ws_size,
                              hipStream_t stream)
{
    const float* coeffs = (const float*)d_in[0];
    const float* x_last = (const float*)d_in[1];
    const float* Wi     = (const float*)d_in[2];
    const float* bi     = (const float*)d_in[3];
    const float* W1     = (const float*)d_in[4];
    const float* b1     = (const float*)d_in[5];
    const float* W2     = (const float*)d_in[6];
    const float* b2     = (const float*)d_in[7];
    const float* W3     = (const float*)d_in[8];
    const float* b3     = (const float*)d_in[9];
    const float* Wr     = (const float*)d_in[10];
    const float* br     = (const float*)d_in[11];
    unsigned short* wf  = (unsigned short*)d_ws;
    float*        kbuf  = (float*)((char*)d_ws + KBUF_BYTE);
    unsigned int* flgs  = (unsigned int*)((char*)d_ws + FLG_BYTE);

    size_t wcap = ws_size / 2;
    int wl = (wcap > (size_t)WF_TOTAL2) ? WF_TOTAL2 : (int)wcap;

    prep_kernel<<<(524288 + 255) / 256, 256, 0, stream>>>(W3, wf, 4, 4096, 524288, OFF_W3, wl);
    prep_kernel<<<(4096   + 255) / 256, 256, 0, stream>>>(Wi, wf, 1, 128,  4096,   OFF_WI, wl);
    prep_kernel<<<(16384  + 255) / 256, 256, 0, stream>>>(W1, wf, 4, 128,  16384,  OFF_W1, wl);
    prep_kernel<<<(16384  + 255) / 256, 256, 0, stream>>>(W2, wf, 4, 128,  16384,  OFF_W2, wl);
    prep_kernel<<<(4096   + 255) / 256, 256, 0, stream>>>(Wr, wf, 4, 32,   4096,   OFF_WR, wl);
    hipMemsetAsync((char*)d_ws + FLG_BYTE, 0, FLG_SIZE, stream);   // zero flags

    cde_kernel<<<512, 256, 0, stream>>>(coeffs, x_last, bi, b1, b2, b3, br, wf,
                                        kbuf, flgs, (float*)d_out);
}

// Round 9
// 3911.774 us; speedup vs baseline: 1.2470x; 1.2470x over previous
//
#include <hip/hip_runtime.h>
#include <math.h>

typedef __attribute__((ext_vector_type(8))) short v8s;
typedef __attribute__((ext_vector_type(4))) float v4f;

#define AP 136              // padded LDS row stride (shorts); 272 B rows keep 16B align
#define OFF_W3 0
#define OFF_WI 524288
#define OFF_W1 528384
#define OFF_W2 544768
#define OFF_WR 561152
#define LO     565248       // lo-residual region offset (shorts)
#define WF_TOTAL2 1130496   // hi+lo regions (shorts, 2.26 MB)
#define KBUF_BYTE 2260992   // float kbuf[16 bg][2 par][2048]  (256 KB)
#define FLG_BYTE  2523136   // uint flags[16 bg][64 wv] @ 16 B spacing (16 KB used)
#define PREP_W    565248    // weight-shuffle thread count
#define PREP_TOT  573440    // + 8192 flag-zeroing threads (32 KB)

static __device__ __forceinline__ float bf2f(unsigned short s){
    union { unsigned u; float f; } v; v.u = ((unsigned)s) << 16; return v.f;
}
static __device__ __forceinline__ unsigned short f2bf(float f){
    union { float ff; unsigned u; } v; v.ff = f;
    return (unsigned short)((v.u + 0x7FFFu + ((v.u >> 16) & 1u)) >> 16);
}
// triple split: v = h + m + l + eps, |eps| <= 2^-27 |v|
static __device__ __forceinline__ void split3(float v, unsigned short& h,
                                              unsigned short& m, unsigned short& l){
    h = f2bf(v);  float r1 = v - bf2f(h);
    m = f2bf(r1); float r2 = r1 - bf2f(m);
    l = f2bf(r2);
}
static __device__ __forceinline__ float softplus_f(float x){
    float t = __builtin_amdgcn_exp2f(x * 1.44269504088896341f);
    float r = 0.69314718055994531f * __builtin_amdgcn_logf(1.0f + t);
    return (x > 20.0f) ? x : r;
}
static __device__ __forceinline__ float tanh_f(float x){
    float xc = fminf(fmaxf(x, -9.0f), 9.0f);
    float t = __builtin_amdgcn_exp2f(xc * 2.8853900817779268f); // e^{2x}
    float d = t + 1.0f;
    float r = __builtin_amdgcn_rcpf(d);
    r = r * (2.0f - d * r);                                     // NR refine
    return (t - 1.0f) * r;
}

#define MFMA(acc, a, b) acc = __builtin_amdgcn_mfma_f32_16x16x32_bf16(a, b, acc, 0, 0, 0)

// ---------------------------------------------------------------------------
// Merged prep: fp32 weights -> bf16 hi+lo B-fragment layout, + flag zeroing.
// frag elem = W[kt*32 + (lane>>4)*8 + j][nt*16 + (lane&15)]
// ---------------------------------------------------------------------------
__global__ void prep_kernel(const float* __restrict__ W3,
                            const float* __restrict__ Wi,
                            const float* __restrict__ W1,
                            const float* __restrict__ W2,
                            const float* __restrict__ Wr,
                            unsigned short* __restrict__ dst,
                            unsigned int* __restrict__ flg,
                            int wlimit){
    int g = blockIdx.x * 256 + threadIdx.x;
    if (g >= PREP_TOT) return;
    if (g >= PREP_W){ int t = g - PREP_W; if (t < 8192) flg[t] = 0u; return; }

    const float* W; int KT, N, t;
    if      (g < OFF_WI){ W = W3; KT = 4; N = 4096; t = g; }
    else if (g < OFF_W1){ W = Wi; KT = 1; N = 128;  t = g - OFF_WI; }
    else if (g < OFF_W2){ W = W1; KT = 4; N = 128;  t = g - OFF_W1; }
    else if (g < OFF_WR){ W = W2; KT = 4; N = 128;  t = g - OFF_W2; }
    else               { W = Wr; KT = 4; N = 32;   t = g - OFF_WR; }

    int j  = t & 7;
    int l  = (t >> 3) & 63;
    int t2 = t >> 9;
    int kt = t2 % KT;
    int nt = t2 / KT;
    int row = kt * 32 + (l >> 4) * 8 + j;
    int col = nt * 16 + (l & 15);
    float w = W[(size_t)row * N + col];
    unsigned short h = f2bf(w);
    if (g < wlimit)      dst[g]      = h;
    if (g + LO < wlimit) dst[g + LO] = f2bf(w - bf2f(h));
}

// B-fragment pair (two 16-col tiles), hi+lo
struct BFrag { v8s h[2][4]; v8s l[2][4]; };

static __device__ __forceinline__ BFrag load_bfrag(const unsigned short* __restrict__ wf,
                                                   int wbase, int p, int lane){
    BFrag f;
#pragma unroll
    for (int i = 0; i < 2; ++i){
        int nt = 2 * p + i;
#pragma unroll
        for (int kt = 0; kt < 4; ++kt){
            int o = wbase + ((nt * 4 + kt) * 64 + lane) * 8;
            f.h[i][kt] = *(const v8s*)&wf[o];
            f.l[i][kt] = *(const v8s*)&wf[o + LO];
        }
    }
    return f;
}

// 40-MFMA pair compute, exact r6 ordering (bit-identical accumulation)
static __device__ __forceinline__ void mfma_pair(v4f& acc0, v4f& acc1,
    const v8s* ah, const v8s* am, const v8s* al, const BFrag& f){
#pragma unroll
    for (int kt = 0; kt < 4; ++kt){
        MFMA(acc0, ah[kt], f.h[0][kt]); MFMA(acc0, am[kt], f.h[0][kt]); MFMA(acc0, al[kt], f.h[0][kt]);
        MFMA(acc0, ah[kt], f.l[0][kt]); MFMA(acc0, am[kt], f.l[0][kt]);
        MFMA(acc1, ah[kt], f.h[1][kt]); MFMA(acc1, am[kt], f.h[1][kt]); MFMA(acc1, al[kt], f.h[1][kt]);
        MFMA(acc1, ah[kt], f.l[1][kt]); MFMA(acc1, am[kt], f.l[1][kt]);
    }
}

// wave-0 poll of the 64 per-wave producer flags (one per lane)
static __device__ __forceinline__ void poll_flags64(const unsigned int* __restrict__ teamflg,
                                                    unsigned tgt, int lane){
    unsigned it = 0;
    for (;;){
        unsigned fv = __hip_atomic_load(&teamflg[lane * 4], __ATOMIC_RELAXED,
                                        __HIP_MEMORY_SCOPE_AGENT);
        if (__all((int)(fv >= tgt))) break;
        if (++it >= (1u << 22)) break;   // terminate-don't-hang safety
        __builtin_amdgcn_s_sleep(2);
    }
}

// ---------------------------------------------------------------------------
// gemm5 (5-MFMA split GEMM, global B-frags) -- Wi prologue / Wr epilogue only
// ---------------------------------------------------------------------------
template<int KT, int MODE>
static __device__ __forceinline__ void gemm5(
    const unsigned short* __restrict__ wf, int wbase, int npairs,
    const unsigned short* Ah, const unsigned short* Am, const unsigned short* Al,
    float* zx,
    const float* __restrict__ bias_g,
    const float* __restrict__ xlast, float* __restrict__ outg, int bg)
{
    const int tid  = threadIdx.x;
    const int lane = tid & 63;
    const int wid  = tid >> 6;
    const int l15  = lane & 15;
    const int q    = lane >> 4;

    v8s ah[KT], am[KT], al[KT];
#pragma unroll
    for (int kt = 0; kt < KT; ++kt){
        ah[kt] = *(const v8s*)&Ah[l15 * AP + kt * 32 + q * 8];
        am[kt] = *(const v8s*)&Am[l15 * AP + kt * 32 + q * 8];
        al[kt] = *(const v8s*)&Al[l15 * AP + kt * 32 + q * 8];
    }

    for (int p = wid; p < npairs; p += 4){
        const int nt0 = 2 * p, nt1 = 2 * p + 1;
        v4f acc0 = {0.f, 0.f, 0.f, 0.f};
        v4f acc1 = {0.f, 0.f, 0.f, 0.f};
#pragma unroll
        for (int kt = 0; kt < KT; ++kt){
            int o0 = wbase + ((nt0 * KT + kt) * 64 + lane) * 8;
            int o1 = wbase + ((nt1 * KT + kt) * 64 + lane) * 8;
            v8s bh0 = *(const v8s*)&wf[o0];
            v8s bl0 = *(const v8s*)&wf[o0 + LO];
            v8s bh1 = *(const v8s*)&wf[o1];
            v8s bl1 = *(const v8s*)&wf[o1 + LO];
            MFMA(acc0, ah[kt], bh0); MFMA(acc0, am[kt], bh0); MFMA(acc0, al[kt], bh0);
            MFMA(acc0, ah[kt], bl0); MFMA(acc0, am[kt], bl0);
            MFMA(acc1, ah[kt], bh1); MFMA(acc1, am[kt], bh1); MFMA(acc1, al[kt], bh1);
            MFMA(acc1, ah[kt], bl1); MFMA(acc1, am[kt], bl1);
        }
        const int c0 = nt0 * 16 + l15, c1 = nt1 * 16 + l15;

        if (MODE == 0){
#pragma unroll
            for (int r = 0; r < 4; ++r){
                int b = q * 4 + r;
                zx[b * 128 + c0] = acc0[r] + bias_g[c0];
                zx[b * 128 + c1] = acc1[r] + bias_g[c1];
            }
        } else { // MODE 4
#pragma unroll
            for (int r = 0; r < 4; ++r){
                int b = q * 4 + r, gb = bg * 16 + b;
                outg[gb * 32 + c0] = acc0[r] + bias_g[c0] + xlast[gb * 32 + c0];
                outg[gb * 32 + c1] = acc1[r] + bias_g[c1] + xlast[gb * 32 + c1];
            }
        }
    }
}

// ---------------------------------------------------------------------------
// Persistent team kernel: 256 blocks = 16 batch-groups x 16-block teams
// (team XCD-local). All weights register-cached. Per-wave release flags,
// wave-0-only MALL polling + LDS go-counter for the other waves.
// ---------------------------------------------------------------------------
__global__ __launch_bounds__(256, 1) void cde_kernel(
    const float* __restrict__ coeffs,
    const float* __restrict__ x_last,
    const float* __restrict__ bi,
    const float* __restrict__ b1,
    const float* __restrict__ b2,
    const float* __restrict__ b3,
    const float* __restrict__ br,
    const unsigned short* __restrict__ wf,
    float* __restrict__ kbuf,
    unsigned int* __restrict__ flgs,
    float* __restrict__ outg)
{
    __shared__ unsigned short A0h[16*AP] __attribute__((aligned(16)));
    __shared__ unsigned short A0m[16*AP] __attribute__((aligned(16)));
    __shared__ unsigned short A0l[16*AP] __attribute__((aligned(16)));
    __shared__ unsigned short A1h[16*AP] __attribute__((aligned(16)));
    __shared__ unsigned short A1m[16*AP] __attribute__((aligned(16)));
    __shared__ unsigned short A1l[16*AP] __attribute__((aligned(16)));
    __shared__ unsigned short A2h[16*AP] __attribute__((aligned(16)));
    __shared__ unsigned short A2m[16*AP] __attribute__((aligned(16)));
    __shared__ unsigned short A2l[16*AP] __attribute__((aligned(16)));
    __shared__ float dval[512];
    __shared__ float zx[2048];
    __shared__ unsigned go;

    const int tid  = threadIdx.x;
    const int lane = tid & 63;
    const int wid  = tid >> 6;
    const int l15  = lane & 15;
    const int q    = lane >> 4;
    const int bx   = blockIdx.x;
    const int bg   = (bx & 7) * 2 + (bx >> 7);   // team members share bx%8 (XCD)
    const int tr   = (bx >> 3) & 15;

    float*        kb0     = kbuf + bg * 4096;    // [par][2048]
    unsigned int* teamflg = flgs + bg * 256;     // 64 flags @ 16 B (4 uints)
    unsigned int* myflag  = teamflg + (tr * 4 + wid) * 4;

    if (tid == 0) go = 0u;
    for (int e = tid; e < 16*AP; e += 256){
        A0h[e]=0; A0m[e]=0; A0l[e]=0; A1h[e]=0; A1m[e]=0; A1l[e]=0;
        A2h[e]=0; A2m[e]=0; A2l[e]=0;
    }

    // register-cached weight fragments + biases
    v8s w3h[2][2][4], w3l[2][2][4];   // [pi][tile][kt]
#pragma unroll
    for (int pi = 0; pi < 2; ++pi){
        int p = wid + 4 * pi;
#pragma unroll
        for (int i = 0; i < 2; ++i){
            int ntg = tr * 16 + 2 * p + i;
#pragma unroll
            for (int kt = 0; kt < 4; ++kt){
                int o = ((ntg * 4 + kt) * 64 + lane) * 8;   // OFF_W3 = 0
                w3h[pi][i][kt] = *(const v8s*)&wf[o];
                w3l[pi][i][kt] = *(const v8s*)&wf[o + LO];
            }
        }
    }
    BFrag w1f = load_bfrag(wf, OFF_W1, wid, lane);
    BFrag w2f = load_bfrag(wf, OFF_W2, wid, lane);
    const int c0 = wid * 32 + l15, c1 = c0 + 16;
    const float b1v0 = b1[c0], b1v1 = b1[c1];
    const float b2v0 = b2[c0], b2v1 = b2[c1];
    float b3v[2][2];
#pragma unroll
    for (int pi = 0; pi < 2; ++pi){
        int cg0 = tr * 256 + (wid + 4 * pi) * 32 + l15;
        b3v[pi][0] = b3[cg0]; b3v[pi][1] = b3[cg0 + 16];
    }

    const int arow = tid >> 4;
    const int acol = (tid & 15) * 8;

    // prologue: z0 = a0 @ Wi + bi
    for (int e = tid; e < 512; e += 256){
        int r = e >> 5, c = e & 31;
        float v = coeffs[((size_t)(bg * 16 + r) * 64) * 128 + c];
        unsigned short h, m, l; split3(v, h, m, l);
        A0h[r*AP+c] = h; A0m[r*AP+c] = m; A0l[r*AP+c] = l;
    }
    __syncthreads();
    gemm5<1, 0>(wf, OFF_WI, 4, A0h, A0m, A0l, zx, bi, nullptr, nullptr, bg);
    __syncthreads();

    float zp[8], kap[8], k1p[8], k2p[8];
#pragma unroll
    for (int i = 0; i < 8; ++i){ zp[i] = zx[tid*8 + i]; kap[i]=0.f; k1p[i]=0.f; k2p[i]=0.f; }

    // coeff fetch helper indices (2 dval elems per thread: e0=tid, e1=tid+256)
    const int e0r = tid >> 5,        e0c = tid & 31;
    const int e1r = (tid + 256) >> 5, e1c = tid & 31;

    // pre-loop: dval(0) + A0 stage for stage 0 (sub=0 -> from zp)
    {
        size_t base0 = ((size_t)(bg * 16 + e0r) * 64 + 0) * 128;
        size_t base1 = ((size_t)(bg * 16 + e1r) * 64 + 0) * 128;
        dval[tid]       = coeffs[base0 + 32 + e0c];
        dval[tid + 256] = coeffs[base1 + 32 + e1c];
        v8s vh, vm, vl;
#pragma unroll
        for (int i = 0; i < 8; ++i){
            unsigned short h, m, l; split3(zp[i], h, m, l);
            vh[i] = (short)h; vm[i] = (short)m; vl[i] = (short)l;
        }
        *(v8s*)&A0h[arow*AP + acol] = vh;
        *(v8s*)&A0m[arow*AP + acol] = vm;
        *(v8s*)&A0l[arow*AP + acol] = vl;
    }

    for (int st = 0; st < 256; ++st){
        const int sub = st & 3;
        __syncthreads();                       // (1) A0 + dval visible
        {   // W1 -> A1
            v8s ah[4], am[4], al[4];
#pragma unroll
            for (int kt = 0; kt < 4; ++kt){
                ah[kt] = *(const v8s*)&A0h[l15*AP + kt*32 + q*8];
                am[kt] = *(const v8s*)&A0m[l15*AP + kt*32 + q*8];
                al[kt] = *(const v8s*)&A0l[l15*AP + kt*32 + q*8];
            }
            v4f acc0 = {0.f,0.f,0.f,0.f}, acc1 = {0.f,0.f,0.f,0.f};
            mfma_pair(acc0, acc1, ah, am, al, w1f);
#pragma unroll
            for (int r = 0; r < 4; ++r){
                int b = q * 4 + r;
                float v0 = softplus_f(acc0[r] + b1v0);
                float v1 = softplus_f(acc1[r] + b1v1);
                unsigned short h, m, l;
                split3(v0, h, m, l); A1h[b*AP+c0]=h; A1m[b*AP+c0]=m; A1l[b*AP+c0]=l;
                split3(v1, h, m, l); A1h[b*AP+c1]=h; A1m[b*AP+c1]=m; A1l[b*AP+c1]=l;
            }
        }
        __syncthreads();                       // (2)
        {   // W2 -> A2
            v8s ah[4], am[4], al[4];
#pragma unroll
            for (int kt = 0; kt < 4; ++kt){
                ah[kt] = *(const v8s*)&A1h[l15*AP + kt*32 + q*8];
                am[kt] = *(const v8s*)&A1m[l15*AP + kt*32 + q*8];
                al[kt] = *(const v8s*)&A1l[l15*AP + kt*32 + q*8];
            }
            v4f acc0 = {0.f,0.f,0.f,0.f}, acc1 = {0.f,0.f,0.f,0.f};
            mfma_pair(acc0, acc1, ah, am, al, w2f);
#pragma unroll
            for (int r = 0; r < 4; ++r){
                int b = q * 4 + r;
                float v0 = softplus_f(acc0[r] + b2v0);
                float v1 = softplus_f(acc1[r] + b2v1);
                unsigned short h, m, l;
                split3(v0, h, m, l); A2h[b*AP+c0]=h; A2m[b*AP+c0]=m; A2l[b*AP+c0]=l;
                split3(v1, h, m, l); A2h[b*AP+c1]=h; A2m[b*AP+c1]=m; A2l[b*AP+c1]=l;
            }
        }
        __syncthreads();                       // (3)
        float* kbw = kb0 + (st & 1) * 2048;
        {   // W3 slice -> k slice -> kbuf; per-wave release flag
            v8s ah[4], am[4], al[4];
#pragma unroll
            for (int kt = 0; kt < 4; ++kt){
                ah[kt] = *(const v8s*)&A2h[l15*AP + kt*32 + q*8];
                am[kt] = *(const v8s*)&A2m[l15*AP + kt*32 + q*8];
                al[kt] = *(const v8s*)&A2l[l15*AP + kt*32 + q*8];
            }
            float dv0[4], dv1[4];
#pragma unroll
            for (int r = 0; r < 4; ++r){
                dv0[r] = dval[(q*4 + r) * 32 + l15];
                dv1[r] = dval[(q*4 + r) * 32 + 16 + l15];
            }
#pragma unroll
            for (int pi = 0; pi < 2; ++pi){
                int p = wid + 4 * pi;
                v4f acc0 = {0.f,0.f,0.f,0.f}, acc1 = {0.f,0.f,0.f,0.f};
#pragma unroll
                for (int kt = 0; kt < 4; ++kt){
                    MFMA(acc0, ah[kt], w3h[pi][0][kt]); MFMA(acc0, am[kt], w3h[pi][0][kt]);
                    MFMA(acc0, al[kt], w3h[pi][0][kt]);
                    MFMA(acc0, ah[kt], w3l[pi][0][kt]); MFMA(acc0, am[kt], w3l[pi][0][kt]);
                    MFMA(acc1, ah[kt], w3h[pi][1][kt]); MFMA(acc1, am[kt], w3h[pi][1][kt]);
                    MFMA(acc1, al[kt], w3h[pi][1][kt]);
                    MFMA(acc1, ah[kt], w3l[pi][1][kt]); MFMA(acc1, am[kt], w3l[pi][1][kt]);
                }
                float s4[4];
#pragma unroll
                for (int r = 0; r < 4; ++r){
                    float u0 = acc0[r] + b3v[pi][0];
                    float u1 = acc1[r] + b3v[pi][1];
                    s4[r] = tanh_f(u0) * dv0[r] + tanh_f(u1) * dv1[r];
                }
#pragma unroll
                for (int sm = 1; sm <= 8; sm <<= 1){
#pragma unroll
                    for (int r = 0; r < 4; ++r) s4[r] += __shfl_xor(s4[r], sm);
                }
                if (l15 == 0){
#pragma unroll
                    for (int r = 0; r < 4; ++r)
                        __hip_atomic_store(&kbw[(q*4 + r) * 128 + tr * 8 + p], s4[r],
                                           __ATOMIC_RELAXED, __HIP_MEMORY_SCOPE_AGENT);
                }
            }
            // per-wave publish: release drains this wave's kbuf stores
            if (lane == 0)
                __hip_atomic_store(myflag, (unsigned)(st + 1),
                                   __ATOMIC_RELEASE, __HIP_MEMORY_SCOPE_AGENT);
        }

        // prefetch next stage's spline coeffs into registers (hides poll)
        const int stp1 = (st < 255) ? st + 1 : 255;
        const int sp   = stp1 >> 2, sb = stp1 & 3;
        int nidx; float nfrac;
        if      (sb == 0){ nidx = sp; nfrac = 0.f; }
        else if (sb == 1){ nidx = sp; nfrac = 1.f / 3.f; }
        else if (sb == 2){ nidx = sp; nfrac = 2.f / 3.f; }
        else { nidx = (sp < 63) ? sp + 1 : 63; nfrac = (sp < 63) ? 0.f : 1.f; }
        float cb0, cc0, cd0, cb1, cc1, cd1;
        {
            size_t base0 = ((size_t)(bg * 16 + e0r) * 64 + nidx) * 128;
            size_t base1 = ((size_t)(bg * 16 + e1r) * 64 + nidx) * 128;
            cb0 = coeffs[base0 + 32 + e0c]; cc0 = coeffs[base0 + 64 + e0c]; cd0 = coeffs[base0 + 96 + e0c];
            cb1 = coeffs[base1 + 32 + e1c]; cc1 = coeffs[base1 + 64 + e1c]; cd1 = coeffs[base1 + 96 + e1c];
        }

        // exchange wait: wave 0 polls MALL flags; waves 1-3 spin on LDS go
        const unsigned tgt = (unsigned)(st + 1);
        if (wid == 0){
            poll_flags64(teamflg, tgt, lane);
            if (lane == 0)
                __hip_atomic_store(&go, tgt, __ATOMIC_RELAXED, __HIP_MEMORY_SCOPE_WORKGROUP);
        } else {
            unsigned it = 0;
            while (__hip_atomic_load(&go, __ATOMIC_RELAXED, __HIP_MEMORY_SCOPE_WORKGROUP) < tgt
                   && ++it < (1u << 22))
                __builtin_amdgcn_s_sleep(1);
        }

        float kv[8];
#pragma unroll
        for (int i = 0; i < 8; ++i)
            kv[i] = __hip_atomic_load(&kbw[tid*8 + i], __ATOMIC_RELAXED,
                                      __HIP_MEMORY_SCOPE_AGENT);
#pragma unroll
        for (int i = 0; i < 8; ++i){
            float k = kv[i];
            if      (sub == 0){ k1p[i] = k; kap[i] = zp[i] + k * (1.f/3.f); }
            else if (sub == 1){ k2p[i] = k; kap[i] = zp[i] + (k - k1p[i] * (1.f/3.f)); }
            else if (sub == 2){ kap[i] = zp[i] + (k1p[i] - k2p[i] + k); }
            else { zp[i] = zp[i] + (6.f*k2p[i] - 2.f*k1p[i]
                                    + 3.f*(kap[i] - zp[i]) + k) * 0.125f; }
        }

        // dval(s+1) + A0 stage for s+1 (no barrier needed until (1))
        dval[tid]       = cb0 + (cc0 + cd0 * nfrac) * nfrac;
        dval[tid + 256] = cb1 + (cc1 + cd1 * nfrac) * nfrac;
        {
            const int nsub = stp1 & 3;
            v8s vh, vm, vl;
#pragma unroll
            for (int i = 0; i < 8; ++i){
                float v = (nsub == 0) ? zp[i] : kap[i];
                unsigned short h, m, l; split3(v, h, m, l);
                vh[i] = (short)h; vm[i] = (short)m; vl[i] = (short)l;
            }
            *(v8s*)&A0h[arow*AP + acol] = vh;
            *(v8s*)&A0m[arow*AP + acol] = vm;
            *(v8s*)&A0l[arow*AP + acol] = vl;
        }
    }

    // epilogue: out = x_last + z @ Wr + br  (team blocks write identical values)
    {
        v8s vh, vm, vl;
#pragma unroll
        for (int i = 0; i < 8; ++i){
            unsigned short h, m, l; split3(zp[i], h, m, l);
            vh[i] = (short)h; vm[i] = (short)m; vl[i] = (short)l;
        }
        *(v8s*)&A0h[arow*AP + acol] = vh;
        *(v8s*)&A0m[arow*AP + acol] = vm;
        *(v8s*)&A0l[arow*AP + acol] = vl;
    }
    __syncthreads();
    gemm5<4, 4>(wf, OFF_WR, 1, A0h, A0m, A0l, nullptr, br, x_last, outg, bg);
}

extern "C" void kernel_launch(void* const* d_in, const int* in_sizes, int n_in,
                              void* d_out, int out_size, void* d_ws, size_t ws_size,
                              hipStream_t stream)
{
    const float* coeffs = (const float*)d_in[0];
    const float* x_last = (const float*)d_in[1];
    const float* Wi     = (const float*)d_in[2];
    const float* bi     = (const float*)d_in[3];
    const float* W1     = (const float*)d_in[4];
    const float* b1     = (const float*)d_in[5];
    const float* W2     = (const float*)d_in[6];
    const float* b2     = (const float*)d_in[7];
    const float* W3     = (const float*)d_in[8];
    const float* b3     = (const float*)d_in[9];
    const float* Wr     = (const float*)d_in[10];
    const float* br     = (const float*)d_in[11];
    unsigned short* wf  = (unsigned short*)d_ws;
    float*        kbuf  = (float*)((char*)d_ws + KBUF_BYTE);
    unsigned int* flgs  = (unsigned int*)((char*)d_ws + FLG_BYTE);

    size_t wcap = ws_size / 2;
    int wl = (wcap > (size_t)WF_TOTAL2) ? WF_TOTAL2 : (int)wcap;

    prep_kernel<<<(PREP_TOT + 255) / 256, 256, 0, stream>>>(W3, Wi, W1, W2, Wr,
                                                            wf, flgs, wl);
    cde_kernel<<<256, 256, 0, stream>>>(coeffs, x_last, bi, b1, b2, b3, br, wf,
                                        kbuf, flgs, (float*)d_out);
}

// Round 10
// 2343.035 us; speedup vs baseline: 2.0820x; 1.6695x over previous
//
#include <hip/hip_runtime.h>
#include <math.h>

typedef __attribute__((ext_vector_type(8))) short v8s;
typedef __attribute__((ext_vector_type(4))) float v4f;

#define AP 136              // padded LDS row stride (shorts); 272 B rows keep 16B align
#define OFF_W3 0
#define OFF_WI 524288
#define OFF_W1 528384
#define OFF_W2 544768
#define OFF_WR 561152
#define LO     565248       // lo-residual region offset (shorts)
#define WF_TOTAL2 1130496   // hi+lo regions (shorts, 2.26 MB)
#define KBUF_BYTE 2260992   // float kbuf[16 bg][2 par][2048]  (256 KB)
#define FLG_BYTE  2523136   // uint flags[16 bg][64 wv] @ 16 B spacing (16 KB used)
#define PREP_W    565248    // weight-shuffle thread count
#define PREP_TOT  573440    // + 8192 flag-zeroing threads (32 KB)

static __device__ __forceinline__ float bf2f(unsigned short s){
    union { unsigned u; float f; } v; v.u = ((unsigned)s) << 16; return v.f;
}
static __device__ __forceinline__ unsigned short f2bf(float f){
    union { float ff; unsigned u; } v; v.ff = f;
    return (unsigned short)((v.u + 0x7FFFu + ((v.u >> 16) & 1u)) >> 16);
}
// triple split: v = h + m + l + eps, |eps| <= 2^-27 |v|
static __device__ __forceinline__ void split3(float v, unsigned short& h,
                                              unsigned short& m, unsigned short& l){
    h = f2bf(v);  float r1 = v - bf2f(h);
    m = f2bf(r1); float r2 = r1 - bf2f(m);
    l = f2bf(r2);
}
static __device__ __forceinline__ float softplus_f(float x){
    float t = __builtin_amdgcn_exp2f(x * 1.44269504088896341f);
    float r = 0.69314718055994531f * __builtin_amdgcn_logf(1.0f + t);
    return (x > 20.0f) ? x : r;
}
static __device__ __forceinline__ float tanh_f(float x){
    float xc = fminf(fmaxf(x, -9.0f), 9.0f);
    float t = __builtin_amdgcn_exp2f(xc * 2.8853900817779268f); // e^{2x}
    float d = t + 1.0f;
    float r = __builtin_amdgcn_rcpf(d);
    r = r * (2.0f - d * r);                                     // NR refine
    return (t - 1.0f) * r;
}

#define MFMA(acc, a, b) acc = __builtin_amdgcn_mfma_f32_16x16x32_bf16(a, b, acc, 0, 0, 0)

// ---------------------------------------------------------------------------
// Merged prep: fp32 weights -> bf16 hi+lo B-fragment layout, + flag zeroing.
// frag elem = W[kt*32 + (lane>>4)*8 + j][nt*16 + (lane&15)]
// ---------------------------------------------------------------------------
__global__ void prep_kernel(const float* __restrict__ W3,
                            const float* __restrict__ Wi,
                            const float* __restrict__ W1,
                            const float* __restrict__ W2,
                            const float* __restrict__ Wr,
                            unsigned short* __restrict__ dst,
                            unsigned int* __restrict__ flg,
                            int wlimit){
    int g = blockIdx.x * 256 + threadIdx.x;
    if (g >= PREP_TOT) return;
    if (g >= PREP_W){ int t = g - PREP_W; if (t < 8192) flg[t] = 0u; return; }

    const float* W; int KT, N, t;
    if      (g < OFF_WI){ W = W3; KT = 4; N = 4096; t = g; }
    else if (g < OFF_W1){ W = Wi; KT = 1; N = 128;  t = g - OFF_WI; }
    else if (g < OFF_W2){ W = W1; KT = 4; N = 128;  t = g - OFF_W1; }
    else if (g < OFF_WR){ W = W2; KT = 4; N = 128;  t = g - OFF_W2; }
    else               { W = Wr; KT = 4; N = 32;   t = g - OFF_WR; }

    int j  = t & 7;
    int l  = (t >> 3) & 63;
    int t2 = t >> 9;
    int kt = t2 % KT;
    int nt = t2 / KT;
    int row = kt * 32 + (l >> 4) * 8 + j;
    int col = nt * 16 + (l & 15);
    float w = W[(size_t)row * N + col];
    unsigned short h = f2bf(w);
    if (g < wlimit)      dst[g]      = h;
    if (g + LO < wlimit) dst[g + LO] = f2bf(w - bf2f(h));
}

// ---------------------------------------------------------------------------
// 5-MFMA fragment GEMM (A-triple from LDS x B-double streamed from global).
// 4 waves; wave w handles pair-columns p = w, w+4, ...
// MODE 0: +bias -> zx     MODE 1: +bias, softplus -> triple A-out
// MODE 4: +bias +x_last -> out fp32 global
// ---------------------------------------------------------------------------
template<int KT, int MODE>
static __device__ __forceinline__ void gemm5(
    const unsigned short* __restrict__ wf, int wbase, int npairs,
    const unsigned short* Ah, const unsigned short* Am, const unsigned short* Al,
    unsigned short* Aoh, unsigned short* Aom, unsigned short* Aol,
    float* zx,
    const float* __restrict__ bias_g,
    const float* __restrict__ xlast, float* __restrict__ outg, int bg)
{
    const int tid  = threadIdx.x;
    const int lane = tid & 63;
    const int wid  = tid >> 6;
    const int l15  = lane & 15;
    const int q    = lane >> 4;

    v8s ah[KT], am[KT], al[KT];
#pragma unroll
    for (int kt = 0; kt < KT; ++kt){
        ah[kt] = *(const v8s*)&Ah[l15 * AP + kt * 32 + q * 8];
        am[kt] = *(const v8s*)&Am[l15 * AP + kt * 32 + q * 8];
        al[kt] = *(const v8s*)&Al[l15 * AP + kt * 32 + q * 8];
    }

    for (int p = wid; p < npairs; p += 4){
        const int nt0 = 2 * p, nt1 = 2 * p + 1;
        v4f acc0 = {0.f, 0.f, 0.f, 0.f};
        v4f acc1 = {0.f, 0.f, 0.f, 0.f};
#pragma unroll
        for (int kt = 0; kt < KT; ++kt){
            int o0 = wbase + ((nt0 * KT + kt) * 64 + lane) * 8;
            int o1 = wbase + ((nt1 * KT + kt) * 64 + lane) * 8;
            v8s bh0 = *(const v8s*)&wf[o0];
            v8s bl0 = *(const v8s*)&wf[o0 + LO];
            v8s bh1 = *(const v8s*)&wf[o1];
            v8s bl1 = *(const v8s*)&wf[o1 + LO];
            MFMA(acc0, ah[kt], bh0); MFMA(acc0, am[kt], bh0); MFMA(acc0, al[kt], bh0);
            MFMA(acc0, ah[kt], bl0); MFMA(acc0, am[kt], bl0);
            MFMA(acc1, ah[kt], bh1); MFMA(acc1, am[kt], bh1); MFMA(acc1, al[kt], bh1);
            MFMA(acc1, ah[kt], bl1); MFMA(acc1, am[kt], bl1);
        }
        const int c0 = nt0 * 16 + l15, c1 = nt1 * 16 + l15;

        if (MODE == 0){
#pragma unroll
            for (int r = 0; r < 4; ++r){
                int b = q * 4 + r;
                zx[b * 128 + c0] = acc0[r] + bias_g[c0];
                zx[b * 128 + c1] = acc1[r] + bias_g[c1];
            }
        } else if (MODE == 1){
#pragma unroll
            for (int r = 0; r < 4; ++r){
                int b = q * 4 + r;
                float v0 = softplus_f(acc0[r] + bias_g[c0]);
                float v1 = softplus_f(acc1[r] + bias_g[c1]);
                unsigned short h, m, l;
                split3(v0, h, m, l); Aoh[b*AP+c0]=h; Aom[b*AP+c0]=m; Aol[b*AP+c0]=l;
                split3(v1, h, m, l); Aoh[b*AP+c1]=h; Aom[b*AP+c1]=m; Aol[b*AP+c1]=l;
            }
        } else { // MODE 4
#pragma unroll
            for (int r = 0; r < 4; ++r){
                int b = q * 4 + r, gb = bg * 16 + b;
                outg[gb * 32 + c0] = acc0[r] + bias_g[c0] + xlast[gb * 32 + c0];
                outg[gb * 32 + c1] = acc1[r] + bias_g[c1] + xlast[gb * 32 + c1];
            }
        }
    }
}

// ---------------------------------------------------------------------------
// Persistent team kernel: 256 blocks = 16 batch-groups x 16-block teams
// (team XCD-local). W3 reg-cached only (no spill). Exchange: relaxed 8B
// atomics + s_waitcnt vmcnt(0) + relaxed per-wave flags (NO release/acquire
// cache maintenance anywhere in the loop).
// ---------------------------------------------------------------------------
__global__ __launch_bounds__(256, 1) void cde_kernel(
    const float* __restrict__ coeffs,
    const float* __restrict__ x_last,
    const float* __restrict__ bi,
    const float* __restrict__ b1,
    const float* __restrict__ b2,
    const float* __restrict__ b3,
    const float* __restrict__ br,
    const unsigned short* __restrict__ wf,
    float* __restrict__ kbuf,
    unsigned int* __restrict__ flgs,
    float* __restrict__ outg)
{
    __shared__ unsigned short A0h[16*AP] __attribute__((aligned(16)));
    __shared__ unsigned short A0m[16*AP] __attribute__((aligned(16)));
    __shared__ unsigned short A0l[16*AP] __attribute__((aligned(16)));
    __shared__ unsigned short A1h[16*AP] __attribute__((aligned(16)));
    __shared__ unsigned short A1m[16*AP] __attribute__((aligned(16)));
    __shared__ unsigned short A1l[16*AP] __attribute__((aligned(16)));
    __shared__ unsigned short A2h[16*AP] __attribute__((aligned(16)));
    __shared__ unsigned short A2m[16*AP] __attribute__((aligned(16)));
    __shared__ unsigned short A2l[16*AP] __attribute__((aligned(16)));
    __shared__ float dval[512];
    __shared__ float zx[2048];

    const int tid  = threadIdx.x;
    const int lane = tid & 63;
    const int wid  = tid >> 6;
    const int l15  = lane & 15;
    const int q    = lane >> 4;
    const int bx   = blockIdx.x;
    const int bg   = (bx & 7) * 2 + (bx >> 7);   // team members share bx%8 (XCD)
    const int tr   = (bx >> 3) & 15;

    float*        kb0     = kbuf + bg * 4096;    // [par][2048]
    unsigned int* teamflg = flgs + bg * 256;     // 64 flags @ 16 B (4 uints)
    unsigned int* myflag  = teamflg + (tr * 4 + wid) * 4;

    for (int e = tid; e < 16*AP; e += 256){
        A0h[e]=0; A0m[e]=0; A0l[e]=0; A1h[e]=0; A1m[e]=0; A1l[e]=0;
        A2h[e]=0; A2m[e]=0; A2l[e]=0;
    }

    // reg-cached W3 slice frags; wave owns ADJACENT pairs p = 2*wid, 2*wid+1
    v8s w3h[2][2][4], w3l[2][2][4];   // [pi][tile][kt]
    float b3v[2][2];
#pragma unroll
    for (int pi = 0; pi < 2; ++pi){
        int p = 2 * wid + pi;
#pragma unroll
        for (int i = 0; i < 2; ++i){
            int ntg = tr * 16 + 2 * p + i;
#pragma unroll
            for (int kt = 0; kt < 4; ++kt){
                int o = ((ntg * 4 + kt) * 64 + lane) * 8;   // OFF_W3 = 0
                w3h[pi][i][kt] = *(const v8s*)&wf[o];
                w3l[pi][i][kt] = *(const v8s*)&wf[o + LO];
            }
        }
        int cg0 = tr * 256 + p * 32 + l15;
        b3v[pi][0] = b3[cg0]; b3v[pi][1] = b3[cg0 + 16];
    }

    const int arow = tid >> 4;
    const int acol = (tid & 15) * 8;

    // prologue: z0 = a0 @ Wi + bi
    for (int e = tid; e < 512; e += 256){
        int r = e >> 5, c = e & 31;
        float v = coeffs[((size_t)(bg * 16 + r) * 64) * 128 + c];
        unsigned short h, m, l; split3(v, h, m, l);
        A0h[r*AP+c] = h; A0m[r*AP+c] = m; A0l[r*AP+c] = l;
    }
    __syncthreads();
    gemm5<1, 0>(wf, OFF_WI, 4, A0h, A0m, A0l, nullptr, nullptr, nullptr,
                zx, bi, nullptr, nullptr, bg);
    __syncthreads();

    float zp[8], kap[8], k1p[8], k2p[8];
#pragma unroll
    for (int i = 0; i < 8; ++i){ zp[i] = zx[tid*8 + i]; kap[i]=0.f; k1p[i]=0.f; k2p[i]=0.f; }

    const int e0r = tid >> 5,         e0c = tid & 31;
    const int e1r = (tid + 256) >> 5, e1c = tid & 31;

    // pre-loop: dval(0) + A0 stage for stage 0 (sub=0 -> from zp)
    {
        size_t base0 = ((size_t)(bg * 16 + e0r) * 64 + 0) * 128;
        size_t base1 = ((size_t)(bg * 16 + e1r) * 64 + 0) * 128;
        dval[tid]       = coeffs[base0 + 32 + e0c];
        dval[tid + 256] = coeffs[base1 + 32 + e1c];
        v8s vh, vm, vl;
#pragma unroll
        for (int i = 0; i < 8; ++i){
            unsigned short h, m, l; split3(zp[i], h, m, l);
            vh[i] = (short)h; vm[i] = (short)m; vl[i] = (short)l;
        }
        *(v8s*)&A0h[arow*AP + acol] = vh;
        *(v8s*)&A0m[arow*AP + acol] = vm;
        *(v8s*)&A0l[arow*AP + acol] = vl;
    }

    for (int st = 0; st < 256; ++st){
        const int sub = st & 3;
        __syncthreads();                       // (1) A0 + dval visible
        gemm5<4, 1>(wf, OFF_W1, 4, A0h, A0m, A0l, A1h, A1m, A1l,
                    nullptr, b1, nullptr, nullptr, bg);
        __syncthreads();                       // (2)
        gemm5<4, 1>(wf, OFF_W2, 4, A1h, A1m, A1l, A2h, A2m, A2l,
                    nullptr, b2, nullptr, nullptr, bg);
        __syncthreads();                       // (3)
        float* kbw = kb0 + (st & 1) * 2048;
        {   // W3 slice (reg frags) -> k slice -> 8B packed relaxed stores
            v8s ah[4], am[4], al[4];
#pragma unroll
            for (int kt = 0; kt < 4; ++kt){
                ah[kt] = *(const v8s*)&A2h[l15*AP + kt*32 + q*8];
                am[kt] = *(const v8s*)&A2m[l15*AP + kt*32 + q*8];
                al[kt] = *(const v8s*)&A2l[l15*AP + kt*32 + q*8];
            }
            float dv0[4], dv1[4];
#pragma unroll
            for (int r = 0; r < 4; ++r){
                dv0[r] = dval[(q*4 + r) * 32 + l15];
                dv1[r] = dval[(q*4 + r) * 32 + 16 + l15];
            }
            float s4p[2][4];
#pragma unroll
            for (int pi = 0; pi < 2; ++pi){
                v4f acc0 = {0.f,0.f,0.f,0.f}, acc1 = {0.f,0.f,0.f,0.f};
#pragma unroll
                for (int kt = 0; kt < 4; ++kt){
                    MFMA(acc0, ah[kt], w3h[pi][0][kt]); MFMA(acc0, am[kt], w3h[pi][0][kt]);
                    MFMA(acc0, al[kt], w3h[pi][0][kt]);
                    MFMA(acc0, ah[kt], w3l[pi][0][kt]); MFMA(acc0, am[kt], w3l[pi][0][kt]);
                    MFMA(acc1, ah[kt], w3h[pi][1][kt]); MFMA(acc1, am[kt], w3h[pi][1][kt]);
                    MFMA(acc1, al[kt], w3h[pi][1][kt]);
                    MFMA(acc1, ah[kt], w3l[pi][1][kt]); MFMA(acc1, am[kt], w3l[pi][1][kt]);
                }
#pragma unroll
                for (int r = 0; r < 4; ++r){
                    float u0 = acc0[r] + b3v[pi][0];
                    float u1 = acc1[r] + b3v[pi][1];
                    s4p[pi][r] = tanh_f(u0) * dv0[r] + tanh_f(u1) * dv1[r];
                }
#pragma unroll
                for (int sm = 1; sm <= 8; sm <<= 1){
#pragma unroll
                    for (int r = 0; r < 4; ++r) s4p[pi][r] += __shfl_xor(s4p[pi][r], sm);
                }
            }
            if (l15 == 0){
#pragma unroll
                for (int r = 0; r < 4; ++r){
                    union { unsigned long long u; float f[2]; } pk;
                    pk.f[0] = s4p[0][r]; pk.f[1] = s4p[1][r];
                    __hip_atomic_store((unsigned long long*)
                        &kbw[(q*4 + r) * 128 + tr * 8 + 2 * wid], pk.u,
                        __ATOMIC_RELAXED, __HIP_MEMORY_SCOPE_AGENT);
                }
            }
            // publish: wait this wave's MALL stores complete, then relaxed flag
            asm volatile("s_waitcnt vmcnt(0)" ::: "memory");
            if (lane == 0)
                __hip_atomic_store(myflag, (unsigned)(st + 1),
                                   __ATOMIC_RELAXED, __HIP_MEMORY_SCOPE_AGENT);
        }

        // prefetch next stage's spline coeffs into registers (hides poll)
        const int stp1 = (st < 255) ? st + 1 : 255;
        const int sp   = stp1 >> 2, sb = stp1 & 3;
        int nidx; float nfrac;
        if      (sb == 0){ nidx = sp; nfrac = 0.f; }
        else if (sb == 1){ nidx = sp; nfrac = 1.f / 3.f; }
        else if (sb == 2){ nidx = sp; nfrac = 2.f / 3.f; }
        else { nidx = (sp < 63) ? sp + 1 : 63; nfrac = (sp < 63) ? 0.f : 1.f; }
        float cb0, cc0, cd0, cb1, cc1, cd1;
        {
            size_t base0 = ((size_t)(bg * 16 + e0r) * 64 + nidx) * 128;
            size_t base1 = ((size_t)(bg * 16 + e1r) * 64 + nidx) * 128;
            cb0 = coeffs[base0 + 32 + e0c]; cc0 = coeffs[base0 + 64 + e0c]; cd0 = coeffs[base0 + 96 + e0c];
            cb1 = coeffs[base1 + 32 + e1c]; cc1 = coeffs[base1 + 64 + e1c]; cd1 = coeffs[base1 + 96 + e1c];
        }

        // all waves poll the 64 per-wave flags (relaxed, no cache ops)
        {
            const unsigned tgt = (unsigned)(st + 1);
            unsigned it = 0;
            for (;;){
                unsigned fv = __hip_atomic_load(&teamflg[lane * 4], __ATOMIC_RELAXED,
                                                __HIP_MEMORY_SCOPE_AGENT);
                if (__all((int)(fv >= tgt))) break;
                if (++it >= (1u << 22)) break;   // terminate-don't-hang safety
                __builtin_amdgcn_s_sleep(2);
            }
        }

        // 8B packed relaxed kv loads (4 transactions/thread)
        float kv[8];
#pragma unroll
        for (int i = 0; i < 4; ++i){
            union { unsigned long long u; float f[2]; } pk;
            pk.u = __hip_atomic_load((const unsigned long long*)&kbw[tid*8 + 2*i],
                                     __ATOMIC_RELAXED, __HIP_MEMORY_SCOPE_AGENT);
            kv[2*i] = pk.f[0]; kv[2*i+1] = pk.f[1];
        }
#pragma unroll
        for (int i = 0; i < 8; ++i){
            float k = kv[i];
            if      (sub == 0){ k1p[i] = k; kap[i] = zp[i] + k * (1.f/3.f); }
            else if (sub == 1){ k2p[i] = k; kap[i] = zp[i] + (k - k1p[i] * (1.f/3.f)); }
            else if (sub == 2){ kap[i] = zp[i] + (k1p[i] - k2p[i] + k); }
            else { zp[i] = zp[i] + (6.f*k2p[i] - 2.f*k1p[i]
                                    + 3.f*(kap[i] - zp[i]) + k) * 0.125f; }
        }

        // dval(s+1) + A0 stage for s+1 (no barrier needed until (1))
        dval[tid]       = cb0 + (cc0 + cd0 * nfrac) * nfrac;
        dval[tid + 256] = cb1 + (cc1 + cd1 * nfrac) * nfrac;
        {
            const int nsub = stp1 & 3;
            v8s vh, vm, vl;
#pragma unroll
            for (int i = 0; i < 8; ++i){
                float v = (nsub == 0) ? zp[i] : kap[i];
                unsigned short h, m, l; split3(v, h, m, l);
                vh[i] = (short)h; vm[i] = (short)m; vl[i] = (short)l;
            }
            *(v8s*)&A0h[arow*AP + acol] = vh;
            *(v8s*)&A0m[arow*AP + acol] = vm;
            *(v8s*)&A0l[arow*AP + acol] = vl;
        }
    }

    // epilogue: out = x_last + z @ Wr + br  (team blocks write identical values)
    {
        v8s vh, vm, vl;
#pragma unroll
        for (int i = 0; i < 8; ++i){
            unsigned short h, m, l; split3(zp[i], h, m, l);
            vh[i] = (short)h; vm[i] = (short)m; vl[i] = (short)l;
        }
        *(v8s*)&A0h[arow*AP + acol] = vh;
        *(v8s*)&A0m[arow*AP + acol] = vm;
        *(v8s*)&A0l[arow*AP + acol] = vl;
    }
    __syncthreads();
    gemm5<4, 4>(wf, OFF_WR, 1, A0h, A0m, A0l, nullptr, nullptr, nullptr,
                nullptr, br, x_last, outg, bg);
}

extern "C" void kernel_launch(void* const* d_in, const int* in_sizes, int n_in,
                              void* d_out, int out_size, void* d_ws, size_t ws_size,
                              hipStream_t stream)
{
    const float* coeffs = (const float*)d_in[0];
    const float* x_last = (const float*)d_in[1];
    const float* Wi     = (const float*)d_in[2];
    const float* bi     = (const float*)d_in[3];
    const float* W1     = (const float*)d_in[4];
    const float* b1     = (const float*)d_in[5];
    const float* W2     = (const float*)d_in[6];
    const float* b2     = (const float*)d_in[7];
    const float* W3     = (const float*)d_in[8];
    const float* b3     = (const float*)d_in[9];
    const float* Wr     = (const float*)d_in[10];
    const float* br     = (const float*)d_in[11];
    unsigned short* wf  = (unsigned short*)d_ws;
    float*        kbuf  = (float*)((char*)d_ws + KBUF_BYTE);
    unsigned int* flgs  = (unsigned int*)((char*)d_ws + FLG_BYTE);

    size_t wcap = ws_size / 2;
    int wl = (wcap > (size_t)WF_TOTAL2) ? WF_TOTAL2 : (int)wcap;

    prep_kernel<<<(PREP_TOT + 255) / 256, 256, 0, stream>>>(W3, Wi, W1, W2, Wr,
                                                            wf, flgs, wl);
    cde_kernel<<<256, 256, 0, stream>>>(coeffs, x_last, bi, b1, b2, b3, br, wf,
                                        kbuf, flgs, (float*)d_out);
}

// Round 11
// 2316.500 us; speedup vs baseline: 2.1058x; 1.0115x over previous
//
#include <hip/hip_runtime.h>
#include <math.h>

typedef __attribute__((ext_vector_type(8))) short v8s;
typedef __attribute__((ext_vector_type(4))) float v4f;

#define AP 136              // padded LDS row stride (shorts); 272 B rows keep 16B align
#define OFF_W3 0
#define OFF_WI 524288
#define OFF_W1 528384
#define OFF_W2 544768
#define OFF_WR 561152
#define LO     565248       // lo-residual region offset (shorts)
#define WF_TOTAL2 1130496   // hi+lo regions (shorts, 2.26 MB)
#define KBUF_BYTE 2260992   // legacy: float kbuf[16 bg][2 par][2048]
#define FLG_BYTE  2523136   // legacy: uint flags[16 bg][64 wv] @ 16 B
#define KB8_BYTE  2260992   // tagged: u64 kb8[16 bg][2 par][2048]  (512 KB, overlaps legacy)
#define WS_NEED   2785280   // bytes needed for tagged path
#define PREP_W    565248    // weight-shuffle thread count
#define PREP_Z    65536     // zeroing threads (8 B each over [KB8_BYTE, WS_NEED))
#define PREP_TOT  630784

static __device__ __forceinline__ float bf2f(unsigned short s){
    union { unsigned u; float f; } v; v.u = ((unsigned)s) << 16; return v.f;
}
static __device__ __forceinline__ unsigned short f2bf(float f){
    union { float ff; unsigned u; } v; v.ff = f;
    return (unsigned short)((v.u + 0x7FFFu + ((v.u >> 16) & 1u)) >> 16);
}
// triple split: v = h + m + l + eps, |eps| <= 2^-27 |v|
static __device__ __forceinline__ void split3(float v, unsigned short& h,
                                              unsigned short& m, unsigned short& l){
    h = f2bf(v);  float r1 = v - bf2f(h);
    m = f2bf(r1); float r2 = r1 - bf2f(m);
    l = f2bf(r2);
}
static __device__ __forceinline__ float softplus_f(float x){
    float t = __builtin_amdgcn_exp2f(x * 1.44269504088896341f);
    float r = 0.69314718055994531f * __builtin_amdgcn_logf(1.0f + t);
    return (x > 20.0f) ? x : r;
}
static __device__ __forceinline__ float tanh_f(float x){
    float xc = fminf(fmaxf(x, -9.0f), 9.0f);
    float t = __builtin_amdgcn_exp2f(xc * 2.8853900817779268f); // e^{2x}
    float d = t + 1.0f;
    float r = __builtin_amdgcn_rcpf(d);
    r = r * (2.0f - d * r);                                     // NR refine
    return (t - 1.0f) * r;
}
static __device__ __forceinline__ unsigned long long pack_kt(float k, unsigned tag){
    union { float f; unsigned u; } c; c.f = k;
    return ((unsigned long long)tag << 32) | (unsigned long long)c.u;
}

#define MFMA(acc, a, b) acc = __builtin_amdgcn_mfma_f32_16x16x32_bf16(a, b, acc, 0, 0, 0)

// ---------------------------------------------------------------------------
// Merged prep: fp32 weights -> bf16 hi+lo B-fragment layout, + zero the
// exchange region (kb8 tags / legacy kbuf+flags) with per-entry ws guard.
// frag elem = W[kt*32 + (lane>>4)*8 + j][nt*16 + (lane&15)]
// ---------------------------------------------------------------------------
__global__ void prep_kernel(const float* __restrict__ W3,
                            const float* __restrict__ Wi,
                            const float* __restrict__ W1,
                            const float* __restrict__ W2,
                            const float* __restrict__ Wr,
                            unsigned short* __restrict__ dst,
                            int wlimit, unsigned long long wsbytes){
    int g = blockIdx.x * 256 + threadIdx.x;
    if (g >= PREP_TOT) return;
    if (g >= PREP_W){
        int t = g - PREP_W;
        unsigned long long byte = (unsigned long long)KB8_BYTE + (unsigned long long)t * 8ull;
        if (t < PREP_Z && byte + 8ull <= wsbytes)
            *(unsigned long long*)((char*)dst + byte) = 0ull;
        return;
    }

    const float* W; int KT, N, t;
    if      (g < OFF_WI){ W = W3; KT = 4; N = 4096; t = g; }
    else if (g < OFF_W1){ W = Wi; KT = 1; N = 128;  t = g - OFF_WI; }
    else if (g < OFF_W2){ W = W1; KT = 4; N = 128;  t = g - OFF_W1; }
    else if (g < OFF_WR){ W = W2; KT = 4; N = 128;  t = g - OFF_W2; }
    else               { W = Wr; KT = 4; N = 32;   t = g - OFF_WR; }

    int j  = t & 7;
    int l  = (t >> 3) & 63;
    int t2 = t >> 9;
    int kt = t2 % KT;
    int nt = t2 / KT;
    int row = kt * 32 + (l >> 4) * 8 + j;
    int col = nt * 16 + (l & 15);
    float w = W[(size_t)row * N + col];
    unsigned short h = f2bf(w);
    if (g < wlimit)      dst[g]      = h;
    if (g + LO < wlimit) dst[g + LO] = f2bf(w - bf2f(h));
}

// ---------------------------------------------------------------------------
// 5-MFMA fragment GEMM (A-triple from LDS x B-double streamed from global).
// 4 waves; wave w handles pair-columns p = w, w+4, ...
// MODE 0: +bias -> zx     MODE 1: +bias, softplus -> triple A-out
// MODE 4: +bias +x_last -> out fp32 global
// ---------------------------------------------------------------------------
template<int KT, int MODE>
static __device__ __forceinline__ void gemm5(
    const unsigned short* __restrict__ wf, int wbase, int npairs,
    const unsigned short* Ah, const unsigned short* Am, const unsigned short* Al,
    unsigned short* Aoh, unsigned short* Aom, unsigned short* Aol,
    float* zx,
    const float* __restrict__ bias_g,
    const float* __restrict__ xlast, float* __restrict__ outg, int bg)
{
    const int tid  = threadIdx.x;
    const int lane = tid & 63;
    const int wid  = tid >> 6;
    const int l15  = lane & 15;
    const int q    = lane >> 4;

    v8s ah[KT], am[KT], al[KT];
#pragma unroll
    for (int kt = 0; kt < KT; ++kt){
        ah[kt] = *(const v8s*)&Ah[l15 * AP + kt * 32 + q * 8];
        am[kt] = *(const v8s*)&Am[l15 * AP + kt * 32 + q * 8];
        al[kt] = *(const v8s*)&Al[l15 * AP + kt * 32 + q * 8];
    }

    for (int p = wid; p < npairs; p += 4){
        const int nt0 = 2 * p, nt1 = 2 * p + 1;
        v4f acc0 = {0.f, 0.f, 0.f, 0.f};
        v4f acc1 = {0.f, 0.f, 0.f, 0.f};
#pragma unroll
        for (int kt = 0; kt < KT; ++kt){
            int o0 = wbase + ((nt0 * KT + kt) * 64 + lane) * 8;
            int o1 = wbase + ((nt1 * KT + kt) * 64 + lane) * 8;
            v8s bh0 = *(const v8s*)&wf[o0];
            v8s bl0 = *(const v8s*)&wf[o0 + LO];
            v8s bh1 = *(const v8s*)&wf[o1];
            v8s bl1 = *(const v8s*)&wf[o1 + LO];
            MFMA(acc0, ah[kt], bh0); MFMA(acc0, am[kt], bh0); MFMA(acc0, al[kt], bh0);
            MFMA(acc0, ah[kt], bl0); MFMA(acc0, am[kt], bl0);
            MFMA(acc1, ah[kt], bh1); MFMA(acc1, am[kt], bh1); MFMA(acc1, al[kt], bh1);
            MFMA(acc1, ah[kt], bl1); MFMA(acc1, am[kt], bl1);
        }
        const int c0 = nt0 * 16 + l15, c1 = nt1 * 16 + l15;

        if (MODE == 0){
#pragma unroll
            for (int r = 0; r < 4; ++r){
                int b = q * 4 + r;
                zx[b * 128 + c0] = acc0[r] + bias_g[c0];
                zx[b * 128 + c1] = acc1[r] + bias_g[c1];
            }
        } else if (MODE == 1){
#pragma unroll
            for (int r = 0; r < 4; ++r){
                int b = q * 4 + r;
                float v0 = softplus_f(acc0[r] + bias_g[c0]);
                float v1 = softplus_f(acc1[r] + bias_g[c1]);
                unsigned short h, m, l;
                split3(v0, h, m, l); Aoh[b*AP+c0]=h; Aom[b*AP+c0]=m; Aol[b*AP+c0]=l;
                split3(v1, h, m, l); Aoh[b*AP+c1]=h; Aom[b*AP+c1]=m; Aol[b*AP+c1]=l;
            }
        } else { // MODE 4
#pragma unroll
            for (int r = 0; r < 4; ++r){
                int b = q * 4 + r, gb = bg * 16 + b;
                outg[gb * 32 + c0] = acc0[r] + bias_g[c0] + xlast[gb * 32 + c0];
                outg[gb * 32 + c1] = acc1[r] + bias_g[c1] + xlast[gb * 32 + c1];
            }
        }
    }
}

// ---------------------------------------------------------------------------
// Persistent team kernel: 256 blocks = 16 batch-groups x 16-block teams
// (team XCD-local). W3 reg-cached. Exchange (tagged): self-validating
// {f32 k, u32 stage} 8B relaxed atomics -- no vmcnt, no flags, poll IS the
// data load. Legacy r10 exchange kept as fallback for small ws.
// ---------------------------------------------------------------------------
__global__ __launch_bounds__(256, 1) void cde_kernel(
    const float* __restrict__ coeffs,
    const float* __restrict__ x_last,
    const float* __restrict__ bi,
    const float* __restrict__ b1,
    const float* __restrict__ b2,
    const float* __restrict__ b3,
    const float* __restrict__ br,
    const unsigned short* __restrict__ wf,
    float* __restrict__ kbuf,
    unsigned int* __restrict__ flgs,
    unsigned long long* __restrict__ kb8,
    int tagged,
    float* __restrict__ outg)
{
    __shared__ unsigned short A0h[16*AP] __attribute__((aligned(16)));
    __shared__ unsigned short A0m[16*AP] __attribute__((aligned(16)));
    __shared__ unsigned short A0l[16*AP] __attribute__((aligned(16)));
    __shared__ unsigned short A1h[16*AP] __attribute__((aligned(16)));
    __shared__ unsigned short A1m[16*AP] __attribute__((aligned(16)));
    __shared__ unsigned short A1l[16*AP] __attribute__((aligned(16)));
    __shared__ unsigned short A2h[16*AP] __attribute__((aligned(16)));
    __shared__ unsigned short A2m[16*AP] __attribute__((aligned(16)));
    __shared__ unsigned short A2l[16*AP] __attribute__((aligned(16)));
    __shared__ float dval[512];
    __shared__ float zx[2048];

    const int tid  = threadIdx.x;
    const int lane = tid & 63;
    const int wid  = tid >> 6;
    const int l15  = lane & 15;
    const int q    = lane >> 4;
    const int bx   = blockIdx.x;
    const int bg   = (bx & 7) * 2 + (bx >> 7);   // team members share bx%8 (XCD)
    const int tr   = (bx >> 3) & 15;

    float*              kb0     = kbuf + bg * 4096;   // legacy [par][2048]
    unsigned long long* kb80    = kb8  + bg * 4096;   // tagged [par][2048]
    unsigned int*       teamflg = flgs + bg * 256;    // legacy 64 flags @ 16 B
    unsigned int*       myflag  = teamflg + (tr * 4 + wid) * 4;

    for (int e = tid; e < 16*AP; e += 256){
        A0h[e]=0; A0m[e]=0; A0l[e]=0; A1h[e]=0; A1m[e]=0; A1l[e]=0;
        A2h[e]=0; A2m[e]=0; A2l[e]=0;
    }

    // reg-cached W3 slice frags; wave owns ADJACENT pairs p = 2*wid, 2*wid+1
    v8s w3h[2][2][4], w3l[2][2][4];   // [pi][tile][kt]
    float b3v[2][2];
#pragma unroll
    for (int pi = 0; pi < 2; ++pi){
        int p = 2 * wid + pi;
#pragma unroll
        for (int i = 0; i < 2; ++i){
            int ntg = tr * 16 + 2 * p + i;
#pragma unroll
            for (int kt = 0; kt < 4; ++kt){
                int o = ((ntg * 4 + kt) * 64 + lane) * 8;   // OFF_W3 = 0
                w3h[pi][i][kt] = *(const v8s*)&wf[o];
                w3l[pi][i][kt] = *(const v8s*)&wf[o + LO];
            }
        }
        int cg0 = tr * 256 + p * 32 + l15;
        b3v[pi][0] = b3[cg0]; b3v[pi][1] = b3[cg0 + 16];
    }

    const int arow = tid >> 4;
    const int acol = (tid & 15) * 8;

    // prologue: z0 = a0 @ Wi + bi
    for (int e = tid; e < 512; e += 256){
        int r = e >> 5, c = e & 31;
        float v = coeffs[((size_t)(bg * 16 + r) * 64) * 128 + c];
        unsigned short h, m, l; split3(v, h, m, l);
        A0h[r*AP+c] = h; A0m[r*AP+c] = m; A0l[r*AP+c] = l;
    }
    __syncthreads();
    gemm5<1, 0>(wf, OFF_WI, 4, A0h, A0m, A0l, nullptr, nullptr, nullptr,
                zx, bi, nullptr, nullptr, bg);
    __syncthreads();

    float zp[8], kap[8], k1p[8], k2p[8];
#pragma unroll
    for (int i = 0; i < 8; ++i){ zp[i] = zx[tid*8 + i]; kap[i]=0.f; k1p[i]=0.f; k2p[i]=0.f; }

    const int e0r = tid >> 5,         e0c = tid & 31;
    const int e1r = (tid + 256) >> 5, e1c = tid & 31;

    // pre-loop: dval(0) + A0 stage for stage 0 (sub=0 -> from zp)
    {
        size_t base0 = ((size_t)(bg * 16 + e0r) * 64 + 0) * 128;
        size_t base1 = ((size_t)(bg * 16 + e1r) * 64 + 0) * 128;
        dval[tid]       = coeffs[base0 + 32 + e0c];
        dval[tid + 256] = coeffs[base1 + 32 + e1c];
        v8s vh, vm, vl;
#pragma unroll
        for (int i = 0; i < 8; ++i){
            unsigned short h, m, l; split3(zp[i], h, m, l);
            vh[i] = (short)h; vm[i] = (short)m; vl[i] = (short)l;
        }
        *(v8s*)&A0h[arow*AP + acol] = vh;
        *(v8s*)&A0m[arow*AP + acol] = vm;
        *(v8s*)&A0l[arow*AP + acol] = vl;
    }

    for (int st = 0; st < 256; ++st){
        const int sub = st & 3;
        __syncthreads();                       // (1) A0 + dval visible
        gemm5<4, 1>(wf, OFF_W1, 4, A0h, A0m, A0l, A1h, A1m, A1l,
                    nullptr, b1, nullptr, nullptr, bg);
        __syncthreads();                       // (2)
        gemm5<4, 1>(wf, OFF_W2, 4, A1h, A1m, A1l, A2h, A2m, A2l,
                    nullptr, b2, nullptr, nullptr, bg);
        __syncthreads();                       // (3)
        float*              kbw  = kb0  + (st & 1) * 2048;
        unsigned long long* kb8w = kb80 + (st & 1) * 2048;
        {   // W3 slice (reg frags) -> k slice -> publish
            v8s ah[4], am[4], al[4];
#pragma unroll
            for (int kt = 0; kt < 4; ++kt){
                ah[kt] = *(const v8s*)&A2h[l15*AP + kt*32 + q*8];
                am[kt] = *(const v8s*)&A2m[l15*AP + kt*32 + q*8];
                al[kt] = *(const v8s*)&A2l[l15*AP + kt*32 + q*8];
            }
            float dv0[4], dv1[4];
#pragma unroll
            for (int r = 0; r < 4; ++r){
                dv0[r] = dval[(q*4 + r) * 32 + l15];
                dv1[r] = dval[(q*4 + r) * 32 + 16 + l15];
            }
            float s4p[2][4];
#pragma unroll
            for (int pi = 0; pi < 2; ++pi){
                v4f acc0 = {0.f,0.f,0.f,0.f}, acc1 = {0.f,0.f,0.f,0.f};
#pragma unroll
                for (int kt = 0; kt < 4; ++kt){
                    MFMA(acc0, ah[kt], w3h[pi][0][kt]); MFMA(acc0, am[kt], w3h[pi][0][kt]);
                    MFMA(acc0, al[kt], w3h[pi][0][kt]);
                    MFMA(acc0, ah[kt], w3l[pi][0][kt]); MFMA(acc0, am[kt], w3l[pi][0][kt]);
                    MFMA(acc1, ah[kt], w3h[pi][1][kt]); MFMA(acc1, am[kt], w3h[pi][1][kt]);
                    MFMA(acc1, al[kt], w3h[pi][1][kt]);
                    MFMA(acc1, ah[kt], w3l[pi][1][kt]); MFMA(acc1, am[kt], w3l[pi][1][kt]);
                }
#pragma unroll
                for (int r = 0; r < 4; ++r){
                    float u0 = acc0[r] + b3v[pi][0];
                    float u1 = acc1[r] + b3v[pi][1];
                    s4p[pi][r] = tanh_f(u0) * dv0[r] + tanh_f(u1) * dv1[r];
                }
#pragma unroll
                for (int sm = 1; sm <= 8; sm <<= 1){
#pragma unroll
                    for (int r = 0; r < 4; ++r) s4p[pi][r] += __shfl_xor(s4p[pi][r], sm);
                }
            }
            if (tagged){
                // self-validating stores: {k, stage tag} per entry; no drain/flag
                if (l15 == 0){
                    const unsigned tg = (unsigned)(st + 1);
#pragma unroll
                    for (int r = 0; r < 4; ++r){
                        int idx = (q*4 + r) * 128 + tr * 8 + 2 * wid;
                        __hip_atomic_store(&kb8w[idx],     pack_kt(s4p[0][r], tg),
                                           __ATOMIC_RELAXED, __HIP_MEMORY_SCOPE_AGENT);
                        __hip_atomic_store(&kb8w[idx + 1], pack_kt(s4p[1][r], tg),
                                           __ATOMIC_RELAXED, __HIP_MEMORY_SCOPE_AGENT);
                    }
                }
            } else {
                if (l15 == 0){
#pragma unroll
                    for (int r = 0; r < 4; ++r){
                        union { unsigned long long u; float f[2]; } pk;
                        pk.f[0] = s4p[0][r]; pk.f[1] = s4p[1][r];
                        __hip_atomic_store((unsigned long long*)
                            &kbw[(q*4 + r) * 128 + tr * 8 + 2 * wid], pk.u,
                            __ATOMIC_RELAXED, __HIP_MEMORY_SCOPE_AGENT);
                    }
                }
                asm volatile("s_waitcnt vmcnt(0)" ::: "memory");
                if (lane == 0)
                    __hip_atomic_store(myflag, (unsigned)(st + 1),
                                       __ATOMIC_RELAXED, __HIP_MEMORY_SCOPE_AGENT);
            }
        }

        // prefetch next stage's spline coeffs into registers (hides wait)
        const int stp1 = (st < 255) ? st + 1 : 255;
        const int sp   = stp1 >> 2, sb = stp1 & 3;
        int nidx; float nfrac;
        if      (sb == 0){ nidx = sp; nfrac = 0.f; }
        else if (sb == 1){ nidx = sp; nfrac = 1.f / 3.f; }
        else if (sb == 2){ nidx = sp; nfrac = 2.f / 3.f; }
        else { nidx = (sp < 63) ? sp + 1 : 63; nfrac = (sp < 63) ? 0.f : 1.f; }
        float cb0, cc0, cd0, cb1, cc1, cd1;
        {
            size_t base0 = ((size_t)(bg * 16 + e0r) * 64 + nidx) * 128;
            size_t base1 = ((size_t)(bg * 16 + e1r) * 64 + nidx) * 128;
            cb0 = coeffs[base0 + 32 + e0c]; cc0 = coeffs[base0 + 64 + e0c]; cd0 = coeffs[base0 + 96 + e0c];
            cb1 = coeffs[base1 + 32 + e1c]; cc1 = coeffs[base1 + 64 + e1c]; cd1 = coeffs[base1 + 96 + e1c];
        }

        float kv[8];
        if (tagged){
            // poll own tagged entries: detection IS the data load
            const unsigned tgt = (unsigned)(st + 1);
            unsigned long long raw[8];
            unsigned it = 0;
            for (;;){
                bool ok = true;
#pragma unroll
                for (int i = 0; i < 8; ++i)
                    raw[i] = __hip_atomic_load(&kb8w[tid*8 + i], __ATOMIC_RELAXED,
                                               __HIP_MEMORY_SCOPE_AGENT);
#pragma unroll
                for (int i = 0; i < 8; ++i)
                    ok = ok && ((unsigned)(raw[i] >> 32) >= tgt);
                if (ok) break;
                if (++it >= (1u << 22)) break;   // terminate-don't-hang safety
                __builtin_amdgcn_s_sleep(1);
            }
#pragma unroll
            for (int i = 0; i < 8; ++i){
                union { unsigned u; float f; } c; c.u = (unsigned)raw[i];
                kv[i] = c.f;
            }
        } else {
            const unsigned tgt = (unsigned)(st + 1);
            unsigned it = 0;
            for (;;){
                unsigned fv = __hip_atomic_load(&teamflg[lane * 4], __ATOMIC_RELAXED,
                                                __HIP_MEMORY_SCOPE_AGENT);
                if (__all((int)(fv >= tgt))) break;
                if (++it >= (1u << 22)) break;
                __builtin_amdgcn_s_sleep(2);
            }
#pragma unroll
            for (int i = 0; i < 4; ++i){
                union { unsigned long long u; float f[2]; } pk;
                pk.u = __hip_atomic_load((const unsigned long long*)&kbw[tid*8 + 2*i],
                                         __ATOMIC_RELAXED, __HIP_MEMORY_SCOPE_AGENT);
                kv[2*i] = pk.f[0]; kv[2*i+1] = pk.f[1];
            }
        }

#pragma unroll
        for (int i = 0; i < 8; ++i){
            float k = kv[i];
            if      (sub == 0){ k1p[i] = k; kap[i] = zp[i] + k * (1.f/3.f); }
            else if (sub == 1){ k2p[i] = k; kap[i] = zp[i] + (k - k1p[i] * (1.f/3.f)); }
            else if (sub == 2){ kap[i] = zp[i] + (k1p[i] - k2p[i] + k); }
            else { zp[i] = zp[i] + (6.f*k2p[i] - 2.f*k1p[i]
                                    + 3.f*(kap[i] - zp[i]) + k) * 0.125f; }
        }

        // dval(s+1) + A0 stage for s+1 (no barrier needed until (1))
        dval[tid]       = cb0 + (cc0 + cd0 * nfrac) * nfrac;
        dval[tid + 256] = cb1 + (cc1 + cd1 * nfrac) * nfrac;
        {
            const int nsub = stp1 & 3;
            v8s vh, vm, vl;
#pragma unroll
            for (int i = 0; i < 8; ++i){
                float v = (nsub == 0) ? zp[i] : kap[i];
                unsigned short h, m, l; split3(v, h, m, l);
                vh[i] = (short)h; vm[i] = (short)m; vl[i] = (short)l;
            }
            *(v8s*)&A0h[arow*AP + acol] = vh;
            *(v8s*)&A0m[arow*AP + acol] = vm;
            *(v8s*)&A0l[arow*AP + acol] = vl;
        }
    }

    // epilogue: out = x_last + z @ Wr + br  (team blocks write identical values)
    {
        v8s vh, vm, vl;
#pragma unroll
        for (int i = 0; i < 8; ++i){
            unsigned short h, m, l; split3(zp[i], h, m, l);
            vh[i] = (short)h; vm[i] = (short)m; vl[i] = (short)l;
        }
        *(v8s*)&A0h[arow*AP + acol] = vh;
        *(v8s*)&A0m[arow*AP + acol] = vm;
        *(v8s*)&A0l[arow*AP + acol] = vl;
    }
    __syncthreads();
    gemm5<4, 4>(wf, OFF_WR, 1, A0h, A0m, A0l, nullptr, nullptr, nullptr,
                nullptr, br, x_last, outg, bg);
}

extern "C" void kernel_launch(void* const* d_in, const int* in_sizes, int n_in,
                              void* d_out, int out_size, void* d_ws, size_t ws_size,
                              hipStream_t stream)
{
    const float* coeffs = (const float*)d_in[0];
    const float* x_last = (const float*)d_in[1];
    const float* Wi     = (const float*)d_in[2];
    const float* bi     = (const float*)d_in[3];
    const float* W1     = (const float*)d_in[4];
    const float* b1     = (const float*)d_in[5];
    const float* W2     = (const float*)d_in[6];
    const float* b2     = (const float*)d_in[7];
    const float* W3     = (const float*)d_in[8];
    const float* b3     = (const float*)d_in[9];
    const float* Wr     = (const float*)d_in[10];
    const float* br     = (const float*)d_in[11];
    unsigned short*     wf   = (unsigned short*)d_ws;
    float*              kbuf = (float*)((char*)d_ws + KBUF_BYTE);
    unsigned int*       flgs = (unsigned int*)((char*)d_ws + FLG_BYTE);
    unsigned long long* kb8  = (unsigned long long*)((char*)d_ws + KB8_BYTE);

    size_t wcap = ws_size / 2;
    int wl = (wcap > (size_t)WF_TOTAL2) ? WF_TOTAL2 : (int)wcap;
    int tagged = (ws_size >= (size_t)WS_NEED) ? 1 : 0;

    prep_kernel<<<(PREP_TOT + 255) / 256, 256, 0, stream>>>(W3, Wi, W1, W2, Wr,
                                                            wf, wl,
                                                            (unsigned long long)ws_size);
    cde_kernel<<<256, 256, 0, stream>>>(coeffs, x_last, bi, b1, b2, b3, br, wf,
                                        kbuf, flgs, kb8, tagged, (float*)d_out);
}

// Round 14
// 1772.521 us; speedup vs baseline: 2.7521x; 1.3069x over previous
//
#include <hip/hip_runtime.h>
#include <math.h>

typedef __attribute__((ext_vector_type(8))) short v8s;
typedef __attribute__((ext_vector_type(4))) float v4f;

#define AP 136              // padded LDS row stride (shorts); 272 B rows keep 16B align
#define OFF_W3 0
#define OFF_WI 524288
#define OFF_W1 528384
#define OFF_W2 544768
#define OFF_WR 561152
#define LO     565248       // lo-residual region offset (shorts)
#define WF_TOTAL2 1130496   // hi+lo regions (shorts, 2.26 MB)
#define KBUF_BYTE 2260992   // float kbuf[16 bg][2 par][2048]  (256 KB)
#define FLG_BYTE  2523136   // uint flags[16 bg][16 tr] @ 16 B spacing (4 KB)
#define WS_END    2527232
#define PREP_W    565248    // weight-shuffle thread count
#define PREP_Z    33280     // zeroing threads: [KBUF_BYTE, WS_END) / 8
#define PREP_TOT  598528

static __device__ __forceinline__ float bf2f(unsigned short s){
    union { unsigned u; float f; } v; v.u = ((unsigned)s) << 16; return v.f;
}
static __device__ __forceinline__ unsigned short f2bf(float f){
    union { float ff; unsigned u; } v; v.ff = f;
    return (unsigned short)((v.u + 0x7FFFu + ((v.u >> 16) & 1u)) >> 16);
}
// triple split: v = h + m + l + eps, |eps| <= 2^-27 |v|
static __device__ __forceinline__ void split3(float v, unsigned short& h,
                                              unsigned short& m, unsigned short& l){
    h = f2bf(v);  float r1 = v - bf2f(h);
    m = f2bf(r1); float r2 = r1 - bf2f(m);
    l = f2bf(r2);
}
static __device__ __forceinline__ float softplus_f(float x){
    float t = __builtin_amdgcn_exp2f(x * 1.44269504088896341f);
    float r = 0.69314718055994531f * __builtin_amdgcn_logf(1.0f + t);
    return (x > 20.0f) ? x : r;
}
static __device__ __forceinline__ float tanh_f(float x){
    float xc = fminf(fmaxf(x, -9.0f), 9.0f);
    float t = __builtin_amdgcn_exp2f(xc * 2.8853900817779268f); // e^{2x}
    float d = t + 1.0f;
    float r = __builtin_amdgcn_rcpf(d);
    r = r * (2.0f - d * r);                                     // NR refine
    return (t - 1.0f) * r;
}

#define MFMA(acc, a, b) acc = __builtin_amdgcn_mfma_f32_16x16x32_bf16(a, b, acc, 0, 0, 0)

// ---------------------------------------------------------------------------
// Merged prep: fp32 weights -> bf16 hi+lo B-fragment layout, + zero the
// exchange region [KBUF_BYTE, WS_END) (kbuf + block flags).
// frag elem = W[kt*32 + (lane>>4)*8 + j][nt*16 + (lane&15)]
// ---------------------------------------------------------------------------
__global__ void prep_kernel(const float* __restrict__ W3,
                            const float* __restrict__ Wi,
                            const float* __restrict__ W1,
                            const float* __restrict__ W2,
                            const float* __restrict__ Wr,
                            unsigned short* __restrict__ dst,
                            int wlimit, unsigned long long wsbytes){
    int g = blockIdx.x * 256 + threadIdx.x;
    if (g >= PREP_TOT) return;
    if (g >= PREP_W){
        int t = g - PREP_W;
        unsigned long long byte = (unsigned long long)KBUF_BYTE + (unsigned long long)t * 8ull;
        if (t < PREP_Z && byte + 8ull <= wsbytes)
            *(unsigned long long*)((char*)dst + byte) = 0ull;
        return;
    }

    const float* W; int KT, N, t;
    if      (g < OFF_WI){ W = W3; KT = 4; N = 4096; t = g; }
    else if (g < OFF_W1){ W = Wi; KT = 1; N = 128;  t = g - OFF_WI; }
    else if (g < OFF_W2){ W = W1; KT = 4; N = 128;  t = g - OFF_W1; }
    else if (g < OFF_WR){ W = W2; KT = 4; N = 128;  t = g - OFF_W2; }
    else               { W = Wr; KT = 4; N = 32;   t = g - OFF_WR; }

    int j  = t & 7;
    int l  = (t >> 3) & 63;
    int t2 = t >> 9;
    int kt = t2 % KT;
    int nt = t2 / KT;
    int row = kt * 32 + (l >> 4) * 8 + j;
    int col = nt * 16 + (l & 15);
    float w = W[(size_t)row * N + col];
    unsigned short h = f2bf(w);
    if (g < wlimit)      dst[g]      = h;
    if (g + LO < wlimit) dst[g + LO] = f2bf(w - bf2f(h));
}

// ---------------------------------------------------------------------------
// 5-MFMA fragment GEMM (A-triple from LDS x B-double streamed from global).
// 4 waves; wave w handles pair-columns p = w, w+4, ...
// MODE 0: +bias -> zx     MODE 1: +bias, softplus -> triple A-out
// MODE 4: +bias +x_last -> out fp32 global
// ---------------------------------------------------------------------------
template<int KT, int MODE>
static __device__ __forceinline__ void gemm5(
    const unsigned short* __restrict__ wf, int wbase, int npairs,
    const unsigned short* Ah, const unsigned short* Am, const unsigned short* Al,
    unsigned short* Aoh, unsigned short* Aom, unsigned short* Aol,
    float* zx,
    const float* __restrict__ bias_g,
    const float* __restrict__ xlast, float* __restrict__ outg, int bg)
{
    const int tid  = threadIdx.x;
    const int lane = tid & 63;
    const int wid  = tid >> 6;
    const int l15  = lane & 15;
    const int q    = lane >> 4;

    v8s ah[KT], am[KT], al[KT];
#pragma unroll
    for (int kt = 0; kt < KT; ++kt){
        ah[kt] = *(const v8s*)&Ah[l15 * AP + kt * 32 + q * 8];
        am[kt] = *(const v8s*)&Am[l15 * AP + kt * 32 + q * 8];
        al[kt] = *(const v8s*)&Al[l15 * AP + kt * 32 + q * 8];
    }

    for (int p = wid; p < npairs; p += 4){
        const int nt0 = 2 * p, nt1 = 2 * p + 1;
        v4f acc0 = {0.f, 0.f, 0.f, 0.f};
        v4f acc1 = {0.f, 0.f, 0.f, 0.f};
#pragma unroll
        for (int kt = 0; kt < KT; ++kt){
            int o0 = wbase + ((nt0 * KT + kt) * 64 + lane) * 8;
            int o1 = wbase + ((nt1 * KT + kt) * 64 + lane) * 8;
            v8s bh0 = *(const v8s*)&wf[o0];
            v8s bl0 = *(const v8s*)&wf[o0 + LO];
            v8s bh1 = *(const v8s*)&wf[o1];
            v8s bl1 = *(const v8s*)&wf[o1 + LO];
            MFMA(acc0, ah[kt], bh0); MFMA(acc0, am[kt], bh0); MFMA(acc0, al[kt], bh0);
            MFMA(acc0, ah[kt], bl0); MFMA(acc0, am[kt], bl0);
            MFMA(acc1, ah[kt], bh1); MFMA(acc1, am[kt], bh1); MFMA(acc1, al[kt], bh1);
            MFMA(acc1, ah[kt], bl1); MFMA(acc1, am[kt], bl1);
        }
        const int c0 = nt0 * 16 + l15, c1 = nt1 * 16 + l15;

        if (MODE == 0){
#pragma unroll
            for (int r = 0; r < 4; ++r){
                int b = q * 4 + r;
                zx[b * 128 + c0] = acc0[r] + bias_g[c0];
                zx[b * 128 + c1] = acc1[r] + bias_g[c1];
            }
        } else if (MODE == 1){
#pragma unroll
            for (int r = 0; r < 4; ++r){
                int b = q * 4 + r;
                float v0 = softplus_f(acc0[r] + bias_g[c0]);
                float v1 = softplus_f(acc1[r] + bias_g[c1]);
                unsigned short h, m, l;
                split3(v0, h, m, l); Aoh[b*AP+c0]=h; Aom[b*AP+c0]=m; Aol[b*AP+c0]=l;
                split3(v1, h, m, l); Aoh[b*AP+c1]=h; Aom[b*AP+c1]=m; Aol[b*AP+c1]=l;
            }
        } else { // MODE 4
#pragma unroll
            for (int r = 0; r < 4; ++r){
                int b = q * 4 + r, gb = bg * 16 + b;
                outg[gb * 32 + c0] = acc0[r] + bias_g[c0] + xlast[gb * 32 + c0];
                outg[gb * 32 + c1] = acc1[r] + bias_g[c1] + xlast[gb * 32 + c1];
            }
        }
    }
}

// ---------------------------------------------------------------------------
// Persistent team kernel: 256 blocks = 16 batch-groups x 16-block teams.
// W3 reg-cached. Exchange (r10 protocol + per-producer BLOCK flags):
// producer: relaxed 8B data stores -> vmcnt(0) per wave -> __syncthreads ->
// tid0 stores ONE block flag. consumer thread: polls ONLY its producer's
// flag (tr = tid&15), loads own kv, updates -- block convergence at the
// top-of-loop barrier.
// ---------------------------------------------------------------------------
__global__ __launch_bounds__(256, 1) void cde_kernel(
    const float* __restrict__ coeffs,
    const float* __restrict__ x_last,
    const float* __restrict__ bi,
    const float* __restrict__ b1,
    const float* __restrict__ b2,
    const float* __restrict__ b3,
    const float* __restrict__ br,
    const unsigned short* __restrict__ wf,
    float* __restrict__ kbuf,
    unsigned int* __restrict__ flgs,
    float* __restrict__ outg)
{
    __shared__ unsigned short A0h[16*AP] __attribute__((aligned(16)));
    __shared__ unsigned short A0m[16*AP] __attribute__((aligned(16)));
    __shared__ unsigned short A0l[16*AP] __attribute__((aligned(16)));
    __shared__ unsigned short A1h[16*AP] __attribute__((aligned(16)));
    __shared__ unsigned short A1m[16*AP] __attribute__((aligned(16)));
    __shared__ unsigned short A1l[16*AP] __attribute__((aligned(16)));
    __shared__ unsigned short A2h[16*AP] __attribute__((aligned(16)));
    __shared__ unsigned short A2m[16*AP] __attribute__((aligned(16)));
    __shared__ unsigned short A2l[16*AP] __attribute__((aligned(16)));
    __shared__ float dval[512];
    __shared__ float zx[2048];

    const int tid  = threadIdx.x;
    const int lane = tid & 63;
    const int wid  = tid >> 6;
    const int l15  = lane & 15;
    const int q    = lane >> 4;
    const int bx   = blockIdx.x;
    const int bg   = (bx & 7) * 2 + (bx >> 7);   // team members share bx%8 (XCD)
    const int tr   = (bx >> 3) & 15;

    float*        kb0     = kbuf + bg * 4096;    // [par][2048]
    unsigned int* teamflg = flgs + bg * 64;      // 16 block flags @ 16 B (4 uints)
    unsigned int* myflag  = teamflg + tr * 4;

    for (int e = tid; e < 16*AP; e += 256){
        A0h[e]=0; A0m[e]=0; A0l[e]=0; A1h[e]=0; A1m[e]=0; A1l[e]=0;
        A2h[e]=0; A2m[e]=0; A2l[e]=0;
    }

    // reg-cached W3 slice frags; wave owns ADJACENT pairs p = 2*wid, 2*wid+1
    v8s w3h[2][2][4], w3l[2][2][4];   // [pi][tile][kt]
    float b3v[2][2];
#pragma unroll
    for (int pi = 0; pi < 2; ++pi){
        int p = 2 * wid + pi;
#pragma unroll
        for (int i = 0; i < 2; ++i){
            int ntg = tr * 16 + 2 * p + i;
#pragma unroll
            for (int kt = 0; kt < 4; ++kt){
                int o = ((ntg * 4 + kt) * 64 + lane) * 8;   // OFF_W3 = 0
                w3h[pi][i][kt] = *(const v8s*)&wf[o];
                w3l[pi][i][kt] = *(const v8s*)&wf[o + LO];
            }
        }
        int cg0 = tr * 256 + p * 32 + l15;
        b3v[pi][0] = b3[cg0]; b3v[pi][1] = b3[cg0 + 16];
    }

    const int arow = tid >> 4;
    const int acol = (tid & 15) * 8;

    // prologue: z0 = a0 @ Wi + bi
    for (int e = tid; e < 512; e += 256){
        int r = e >> 5, c = e & 31;
        float v = coeffs[((size_t)(bg * 16 + r) * 64) * 128 + c];
        unsigned short h, m, l; split3(v, h, m, l);
        A0h[r*AP+c] = h; A0m[r*AP+c] = m; A0l[r*AP+c] = l;
    }
    __syncthreads();
    gemm5<1, 0>(wf, OFF_WI, 4, A0h, A0m, A0l, nullptr, nullptr, nullptr,
                zx, bi, nullptr, nullptr, bg);
    __syncthreads();

    float zp[8], kap[8], k1p[8], k2p[8];
#pragma unroll
    for (int i = 0; i < 8; ++i){ zp[i] = zx[tid*8 + i]; kap[i]=0.f; k1p[i]=0.f; k2p[i]=0.f; }

    const int e0r = tid >> 5,         e0c = tid & 31;
    const int e1r = (tid + 256) >> 5, e1c = tid & 31;

    // pre-loop: dval(0) + A0 stage for stage 0 (sub=0 -> from zp)
    {
        size_t base0 = ((size_t)(bg * 16 + e0r) * 64 + 0) * 128;
        size_t base1 = ((size_t)(bg * 16 + e1r) * 64 + 0) * 128;
        dval[tid]       = coeffs[base0 + 32 + e0c];
        dval[tid + 256] = coeffs[base1 + 32 + e1c];
        v8s vh, vm, vl;
#pragma unroll
        for (int i = 0; i < 8; ++i){
            unsigned short h, m, l; split3(zp[i], h, m, l);
            vh[i] = (short)h; vm[i] = (short)m; vl[i] = (short)l;
        }
        *(v8s*)&A0h[arow*AP + acol] = vh;
        *(v8s*)&A0m[arow*AP + acol] = vm;
        *(v8s*)&A0l[arow*AP + acol] = vl;
    }

    for (int st = 0; st < 256; ++st){
        const int sub = st & 3;
        __syncthreads();                       // (1) A0 + dval visible
        gemm5<4, 1>(wf, OFF_W1, 4, A0h, A0m, A0l, A1h, A1m, A1l,
                    nullptr, b1, nullptr, nullptr, bg);
        __syncthreads();                       // (2)
        gemm5<4, 1>(wf, OFF_W2, 4, A1h, A1m, A1l, A2h, A2m, A2l,
                    nullptr, b2, nullptr, nullptr, bg);
        __syncthreads();                       // (3)
        float* kbw = kb0 + (st & 1) * 2048;
        {   // W3 slice (reg frags) -> k slice -> 8B packed relaxed stores
            v8s ah[4], am[4], al[4];
#pragma unroll
            for (int kt = 0; kt < 4; ++kt){
                ah[kt] = *(const v8s*)&A2h[l15*AP + kt*32 + q*8];
                am[kt] = *(const v8s*)&A2m[l15*AP + kt*32 + q*8];
                al[kt] = *(const v8s*)&A2l[l15*AP + kt*32 + q*8];
            }
            float dv0[4], dv1[4];
#pragma unroll
            for (int r = 0; r < 4; ++r){
                dv0[r] = dval[(q*4 + r) * 32 + l15];
                dv1[r] = dval[(q*4 + r) * 32 + 16 + l15];
            }
            float s4p[2][4];
#pragma unroll
            for (int pi = 0; pi < 2; ++pi){
                v4f acc0 = {0.f,0.f,0.f,0.f}, acc1 = {0.f,0.f,0.f,0.f};
#pragma unroll
                for (int kt = 0; kt < 4; ++kt){
                    MFMA(acc0, ah[kt], w3h[pi][0][kt]); MFMA(acc0, am[kt], w3h[pi][0][kt]);
                    MFMA(acc0, al[kt], w3h[pi][0][kt]);
                    MFMA(acc0, ah[kt], w3l[pi][0][kt]); MFMA(acc0, am[kt], w3l[pi][0][kt]);
                    MFMA(acc1, ah[kt], w3h[pi][1][kt]); MFMA(acc1, am[kt], w3h[pi][1][kt]);
                    MFMA(acc1, al[kt], w3h[pi][1][kt]);
                    MFMA(acc1, ah[kt], w3l[pi][1][kt]); MFMA(acc1, am[kt], w3l[pi][1][kt]);
                }
#pragma unroll
                for (int r = 0; r < 4; ++r){
                    float u0 = acc0[r] + b3v[pi][0];
                    float u1 = acc1[r] + b3v[pi][1];
                    s4p[pi][r] = tanh_f(u0) * dv0[r] + tanh_f(u1) * dv1[r];
                }
#pragma unroll
                for (int sm = 1; sm <= 8; sm <<= 1){
#pragma unroll
                    for (int r = 0; r < 4; ++r) s4p[pi][r] += __shfl_xor(s4p[pi][r], sm);
                }
            }
            if (l15 == 0){
#pragma unroll
                for (int r = 0; r < 4; ++r){
                    union { unsigned long long u; float f[2]; } pk;
                    pk.f[0] = s4p[0][r]; pk.f[1] = s4p[1][r];
                    __hip_atomic_store((unsigned long long*)
                        &kbw[(q*4 + r) * 128 + tr * 8 + 2 * wid], pk.u,
                        __ATOMIC_RELAXED, __HIP_MEMORY_SCOPE_AGENT);
                }
            }
            // publish: every wave drains its own stores; one barrier; ONE
            // block flag (monotone) from tid 0
            asm volatile("s_waitcnt vmcnt(0)" ::: "memory");
            __syncthreads();
            if (tid == 0)
                __hip_atomic_store(myflag, (unsigned)(st + 1),
                                   __ATOMIC_RELAXED, __HIP_MEMORY_SCOPE_AGENT);
        }

        // prefetch next stage's spline coeffs into registers (hides wait)
        const int stp1 = (st < 255) ? st + 1 : 255;
        const int sp   = stp1 >> 2, sb = stp1 & 3;
        int nidx; float nfrac;
        if      (sb == 0){ nidx = sp; nfrac = 0.f; }
        else if (sb == 1){ nidx = sp; nfrac = 1.f / 3.f; }
        else if (sb == 2){ nidx = sp; nfrac = 2.f / 3.f; }
        else { nidx = (sp < 63) ? sp + 1 : 63; nfrac = (sp < 63) ? 0.f : 1.f; }
        float cb0, cc0, cd0, cb1, cc1, cd1;
        {
            size_t base0 = ((size_t)(bg * 16 + e0r) * 64 + nidx) * 128;
            size_t base1 = ((size_t)(bg * 16 + e1r) * 64 + nidx) * 128;
            cb0 = coeffs[base0 + 32 + e0c]; cc0 = coeffs[base0 + 64 + e0c]; cd0 = coeffs[base0 + 96 + e0c];
            cb1 = coeffs[base1 + 32 + e1c]; cc1 = coeffs[base1 + 64 + e1c]; cd1 = coeffs[base1 + 96 + e1c];
        }

        // per-thread wait: only this thread's producer (tr = tid & 15)
        {
            const unsigned tgt = (unsigned)(st + 1);
            const unsigned int* fp = &teamflg[(tid & 15) * 4];
            unsigned it = 0;
            while (__hip_atomic_load(fp, __ATOMIC_RELAXED,
                                     __HIP_MEMORY_SCOPE_AGENT) < tgt
                   && ++it < (1u << 22))
                __builtin_amdgcn_s_sleep(1);
        }

        // 8B packed relaxed kv loads (4 transactions/thread)
        float kv[8];
#pragma unroll
        for (int i = 0; i < 4; ++i){
            union { unsigned long long u; float f[2]; } pk;
            pk.u = __hip_atomic_load((const unsigned long long*)&kbw[tid*8 + 2*i],
                                     __ATOMIC_RELAXED, __HIP_MEMORY_SCOPE_AGENT);
            kv[2*i] = pk.f[0]; kv[2*i+1] = pk.f[1];
        }
#pragma unroll
        for (int i = 0; i < 8; ++i){
            float k = kv[i];
            if      (sub == 0){ k1p[i] = k; kap[i] = zp[i] + k * (1.f/3.f); }
            else if (sub == 1){ k2p[i] = k; kap[i] = zp[i] + (k - k1p[i] * (1.f/3.f)); }
            else if (sub == 2){ kap[i] = zp[i] + (k1p[i] - k2p[i] + k); }
            else { zp[i] = zp[i] + (6.f*k2p[i] - 2.f*k1p[i]
                                    + 3.f*(kap[i] - zp[i]) + k) * 0.125f; }
        }

        // dval(s+1) + A0 stage for s+1 (no barrier needed until (1))
        dval[tid]       = cb0 + (cc0 + cd0 * nfrac) * nfrac;
        dval[tid + 256] = cb1 + (cc1 + cd1 * nfrac) * nfrac;
        {
            const int nsub = stp1 & 3;
            v8s vh, vm, vl;
#pragma unroll
            for (int i = 0; i < 8; ++i){
                float v = (nsub == 0) ? zp[i] : kap[i];
                unsigned short h, m, l; split3(v, h, m, l);
                vh[i] = (short)h; vm[i] = (short)m; vl[i] = (short)l;
            }
            *(v8s*)&A0h[arow*AP + acol] = vh;
            *(v8s*)&A0m[arow*AP + acol] = vm;
            *(v8s*)&A0l[arow*AP + acol] = vl;
        }
    }

    // epilogue: out = x_last + z @ Wr + br  (team blocks write identical values)
    {
        v8s vh, vm, vl;
#pragma unroll
        for (int i = 0; i < 8; ++i){
            unsigned short h, m, l; split3(zp[i], h, m, l);
            vh[i] = (short)h; vm[i] = (short)m; vl[i] = (short)l;
        }
        *(v8s*)&A0h[arow*AP + acol] = vh;
        *(v8s*)&A0m[arow*AP + acol] = vm;
        *(v8s*)&A0l[arow*AP + acol] = vl;
    }
    __syncthreads();
    gemm5<4, 4>(wf, OFF_WR, 1, A0h, A0m, A0l, nullptr, nullptr, nullptr,
                nullptr, br, x_last, outg, bg);
}

extern "C" void kernel_launch(void* const* d_in, const int* in_sizes, int n_in,
                              void* d_out, int out_size, void* d_ws, size_t ws_size,
                              hipStream_t stream)
{
    const float* coeffs = (const float*)d_in[0];
    const float* x_last = (const float*)d_in[1];
    const float* Wi     = (const float*)d_in[2];
    const float* bi     = (const float*)d_in[3];
    const float* W1     = (const float*)d_in[4];
    const float* b1     = (const float*)d_in[5];
    const float* W2     = (const float*)d_in[6];
    const float* b2     = (const float*)d_in[7];
    const float* W3     = (const float*)d_in[8];
    const float* b3     = (const float*)d_in[9];
    const float* Wr     = (const float*)d_in[10];
    const float* br     = (const float*)d_in[11];
    unsigned short* wf   = (unsigned short*)d_ws;
    float*          kbuf = (float*)((char*)d_ws + KBUF_BYTE);
    unsigned int*   flgs = (unsigned int*)((char*)d_ws + FLG_BYTE);

    size_t wcap = ws_size / 2;
    int wl = (wcap > (size_t)WF_TOTAL2) ? WF_TOTAL2 : (int)wcap;

    prep_kernel<<<(PREP_TOT + 255) / 256, 256, 0, stream>>>(W3, Wi, W1, W2, Wr,
                                                            wf, wl,
                                                            (unsigned long long)ws_size);
    cde_kernel<<<256, 256, 0, stream>>>(coeffs, x_last, bi, b1, b2, b3, br, wf,
                                        kbuf, flgs, (float*)d_out);
}